// Round 2
// baseline (44447.449 us; speedup 1.0000x reference)
//
#include <hip/hip_runtime.h>

typedef __bf16 bf16_t;
typedef bf16_t bf16x8 __attribute__((ext_vector_type(8)));
typedef float f32x4 __attribute__((ext_vector_type(4)));

#define B_SZ 256
#define T_SZ 512
#define I_SZ 64
#define H_SZ 256

__device__ __forceinline__ float sigm(float x) { return 1.f / (1.f + __expf(-x)); }
__device__ __forceinline__ float tanhx(float x) {
  x = fminf(fmaxf(x, -15.f), 15.f);
  float e = __expf(-2.f * x);
  return (1.f - e) / (1.f + e);
}

#define MFMA(a, b, c) __builtin_amdgcn_mfma_f32_16x16x32_bf16((a), (b), (c), 0, 0, 0)

// ---------------------------------------------------------------------------
// Layer 0 scan: grid (16 batch-tiles, 2 dirs), block 1024 = 16 waves.
// Block owns 16 batch rows x ALL 256 h-cols -> recurrence is block-local:
// h double-buffered in LDS, c in lane VGPRs, ONE __syncthreads per step.
// Wave w owns h-cols [16w,16w+16) x 4 gates (epilogue lane-local, layout
// col=lane&15, row=quad*4+r). Weights stream from L2 every step.
// LDS pads: hb stride 280 (560B: 16B-aligned, 2-way banks), xb stride 72.
// ---------------------------------------------------------------------------
__global__ __launch_bounds__(1024) void l0_scan(
    const float* __restrict__ x,
    const bf16_t* __restrict__ wih_f, const bf16_t* __restrict__ whhhi_f,
    const bf16_t* __restrict__ whhlo_f, const float* __restrict__ bias_f,
    const bf16_t* __restrict__ wih_b, const bf16_t* __restrict__ whhhi_b,
    const bf16_t* __restrict__ whhlo_b, const float* __restrict__ bias_b,
    bf16_t* __restrict__ h0) {
  const int bt = blockIdx.x;
  const int dir = blockIdx.y;
  const bf16_t* __restrict__ wih  = dir ? wih_b : wih_f;
  const bf16_t* __restrict__ whhh = dir ? whhhi_b : whhhi_f;
  const bf16_t* __restrict__ whhl = dir ? whhlo_b : whhlo_f;
  const float*  __restrict__ bias = dir ? bias_b : bias_f;

  __shared__ bf16_t hb[2][16][280];
  __shared__ bf16_t xb[2][16][72];

  const int tid  = threadIdx.x;
  const int lane = tid & 63;
  const int wv   = tid >> 6;          // 0..15
  const int l15  = lane & 15;
  const int quad = lane >> 4;
  const int koff = quad * 8;
  const int b0   = bt * 16;
  const int j    = wv * 16 + l15;     // h column this lane owns (B n / D col)

  // loop-invariant weight row pointers (pre-offset by koff)
  const bf16_t* wg[4]; const bf16_t* wh[4]; const bf16_t* wl[4];
#pragma unroll
  for (int g = 0; g < 4; ++g) {
    wg[g] = wih  + (size_t)(g * H_SZ + j) * I_SZ + koff;
    wh[g] = whhh + (size_t)(g * H_SZ + j) * H_SZ + koff;
    wl[g] = whhl + (size_t)(g * H_SZ + j) * H_SZ + koff;
  }
  const float bi = bias[j], bf_ = bias[H_SZ + j],
              bg = bias[2 * H_SZ + j], bo = bias[3 * H_SZ + j];

  // init: zero hb[0], stage x_t0 into xb[0]
  for (int i = tid; i < 16 * 280; i += 1024) hb[0][0][i] = (bf16_t)0.f;
  {
    const int row = tid >> 6, col = tid & 63;
    const int t0 = dir ? (T_SZ - 1) : 0;
    xb[0][row][col] = (bf16_t)x[((size_t)(b0 + row) * T_SZ + t0) * I_SZ + col];
  }
  __syncthreads();

  f32x4 c4 = {0.f, 0.f, 0.f, 0.f};

  for (int s = 0; s < T_SZ; ++s) {
    const int cur = s & 1, nxt = cur ^ 1;
    const int t = dir ? (T_SZ - 1 - s) : s;

    // stage next timestep's x tile (into the buffer read last step)
    if (s + 1 < T_SZ) {
      const int row = tid >> 6, col = tid & 63;
      const int tn = dir ? (T_SZ - 2 - s) : (s + 1);
      xb[nxt][row][col] = (bf16_t)x[((size_t)(b0 + row) * T_SZ + tn) * I_SZ + col];
    }

    f32x4 acc[4] = {{0,0,0,0},{0,0,0,0},{0,0,0,0},{0,0,0,0}};

    // input projection: K = 64
#pragma unroll
    for (int kt = 0; kt < I_SZ; kt += 32) {
      bf16x8 a = *(const bf16x8*)&xb[cur][l15][kt + koff];
#pragma unroll
      for (int g = 0; g < 4; ++g)
        acc[g] = MFMA(a, *(const bf16x8*)(wg[g] + kt), acc[g]);
    }
    // recurrent: K = 256, whh split hi+lo (kills systematic bf16 W error)
#pragma unroll 2
    for (int kt = 0; kt < H_SZ; kt += 32) {
      bf16x8 a = *(const bf16x8*)&hb[cur][l15][kt + koff];
#pragma unroll
      for (int g = 0; g < 4; ++g) {
        acc[g] = MFMA(a, *(const bf16x8*)(wh[g] + kt), acc[g]);
        acc[g] = MFMA(a, *(const bf16x8*)(wl[g] + kt), acc[g]);
      }
    }

    // epilogue: lane-local gate combine, c in VGPRs, h -> LDS + global h0
#pragma unroll
    for (int r = 0; r < 4; ++r) {
      const int row = quad * 4 + r;
      float iv = sigm(acc[0][r] + bi);
      float fv = sigm(acc[1][r] + bf_);
      float gv = tanhx(acc[2][r] + bg);
      float ov = sigm(acc[3][r] + bo);
      float cn = fv * c4[r] + iv * gv;
      c4[r] = cn;
      bf16_t hv = (bf16_t)(ov * tanhx(cn));
      hb[nxt][row][j] = hv;
      h0[((size_t)t * B_SZ + b0 + row) * (2 * H_SZ) + dir * H_SZ + j] = hv;
    }
    __syncthreads();
  }
}

// ---------------------------------------------------------------------------
// Layer 1: grid (16 batch-tiles, 2), block 1024.
// y==0: forward full 512-step scan (input = h0[t] tile staged in LDS).
// y==1: backward direction contributes only t=T-1 to the output, which for a
//       time-aligned reverse scan is ONE step from zero state (h=c=0) -> only
//       the input projection, no recurrent part.
// ---------------------------------------------------------------------------
__global__ __launch_bounds__(1024) void l1_scan(
    const bf16_t* __restrict__ h0,
    const bf16_t* __restrict__ wih_f, const bf16_t* __restrict__ whhhi_f,
    const bf16_t* __restrict__ whhlo_f, const float* __restrict__ bias_f,
    const bf16_t* __restrict__ wih_b, const float* __restrict__ bias_b,
    bf16_t* __restrict__ h1f, bf16_t* __restrict__ h1b) {
  const int bt  = blockIdx.x;
  const int isb = blockIdx.y;

  __shared__ bf16_t hb[2][16][280];
  __shared__ bf16_t ib[2][16][520];

  const int tid  = threadIdx.x;
  const int lane = tid & 63;
  const int wv   = tid >> 6;
  const int l15  = lane & 15;
  const int quad = lane >> 4;
  const int koff = quad * 8;
  const int b0   = bt * 16;
  const int j    = wv * 16 + l15;

  if (isb) {  // single-step reverse direction, h=c=0
    {
      const int row = tid >> 6, c8 = (tid & 63) * 8;
      *(bf16x8*)&ib[0][row][c8] =
          *(const bf16x8*)(h0 + ((size_t)(T_SZ - 1) * B_SZ + b0 + row) * 512 + c8);
    }
    __syncthreads();
    const bf16_t* wg[4];
#pragma unroll
    for (int g = 0; g < 4; ++g)
      wg[g] = wih_b + (size_t)(g * H_SZ + j) * 512 + koff;
    f32x4 acc[4] = {{0,0,0,0},{0,0,0,0},{0,0,0,0},{0,0,0,0}};
#pragma unroll 2
    for (int kt = 0; kt < 512; kt += 32) {
      bf16x8 a = *(const bf16x8*)&ib[0][l15][kt + koff];
#pragma unroll
      for (int g = 0; g < 4; ++g)
        acc[g] = MFMA(a, *(const bf16x8*)(wg[g] + kt), acc[g]);
    }
    const float bi = bias_b[j], bf_ = bias_b[H_SZ + j],
                bg = bias_b[2 * H_SZ + j], bo = bias_b[3 * H_SZ + j];
#pragma unroll
    for (int r = 0; r < 4; ++r) {
      const int row = quad * 4 + r;
      float iv = sigm(acc[0][r] + bi);
      float gv = tanhx(acc[2][r] + bg);
      float ov = sigm(acc[3][r] + bo);
      float cn = iv * gv;                      // f*0 + i*g
      (void)bf_;
      h1b[(size_t)(b0 + row) * H_SZ + j] = (bf16_t)(ov * tanhx(cn));
    }
    return;
  }

  // ---- forward scan ----
  const bf16_t* wg[4]; const bf16_t* wh[4]; const bf16_t* wl[4];
#pragma unroll
  for (int g = 0; g < 4; ++g) {
    wg[g] = wih_f   + (size_t)(g * H_SZ + j) * 512 + koff;
    wh[g] = whhhi_f + (size_t)(g * H_SZ + j) * H_SZ + koff;
    wl[g] = whhlo_f + (size_t)(g * H_SZ + j) * H_SZ + koff;
  }
  const float bi = bias_f[j], bf_ = bias_f[H_SZ + j],
              bg = bias_f[2 * H_SZ + j], bo = bias_f[3 * H_SZ + j];

  for (int i = tid; i < 16 * 280; i += 1024) hb[0][0][i] = (bf16_t)0.f;
  {
    const int row = tid >> 6, c8 = (tid & 63) * 8;
    *(bf16x8*)&ib[0][row][c8] =
        *(const bf16x8*)(h0 + ((size_t)(b0 + row)) * 512 + c8);  // t=0
  }
  __syncthreads();

  f32x4 c4 = {0.f, 0.f, 0.f, 0.f};

  for (int s = 0; s < T_SZ; ++s) {
    const int cur = s & 1, nxt = cur ^ 1;

    if (s + 1 < T_SZ) {
      const int row = tid >> 6, c8 = (tid & 63) * 8;
      *(bf16x8*)&ib[nxt][row][c8] =
          *(const bf16x8*)(h0 + ((size_t)(s + 1) * B_SZ + b0 + row) * 512 + c8);
    }

    f32x4 acc[4] = {{0,0,0,0},{0,0,0,0},{0,0,0,0},{0,0,0,0}};

#pragma unroll 2
    for (int kt = 0; kt < 512; kt += 32) {
      bf16x8 a = *(const bf16x8*)&ib[cur][l15][kt + koff];
#pragma unroll
      for (int g = 0; g < 4; ++g)
        acc[g] = MFMA(a, *(const bf16x8*)(wg[g] + kt), acc[g]);
    }
#pragma unroll 2
    for (int kt = 0; kt < H_SZ; kt += 32) {
      bf16x8 a = *(const bf16x8*)&hb[cur][l15][kt + koff];
#pragma unroll
      for (int g = 0; g < 4; ++g) {
        acc[g] = MFMA(a, *(const bf16x8*)(wh[g] + kt), acc[g]);
        acc[g] = MFMA(a, *(const bf16x8*)(wl[g] + kt), acc[g]);
      }
    }

#pragma unroll
    for (int r = 0; r < 4; ++r) {
      const int row = quad * 4 + r;
      float iv = sigm(acc[0][r] + bi);
      float fv = sigm(acc[1][r] + bf_);
      float gv = tanhx(acc[2][r] + bg);
      float ov = sigm(acc[3][r] + bo);
      float cn = fv * c4[r] + iv * gv;
      c4[r] = cn;
      bf16_t hv = (bf16_t)(ov * tanhx(cn));
      hb[nxt][row][j] = hv;
      if (s == T_SZ - 1) h1f[(size_t)(b0 + row) * H_SZ + j] = hv;
    }
    __syncthreads();
  }
}

// ---------------------------------------------------------------------------
// prep + head
// ---------------------------------------------------------------------------
__global__ void k_cvt(const float* __restrict__ s, bf16_t* __restrict__ d, int n) {
  int i = blockIdx.x * 256 + threadIdx.x;
  if (i < n) d[i] = (bf16_t)s[i];
}
__global__ void k_split(const float* __restrict__ s, bf16_t* __restrict__ hi,
                        bf16_t* __restrict__ lo, int n) {
  int i = blockIdx.x * 256 + threadIdx.x;
  if (i < n) {
    float v = s[i];
    bf16_t h = (bf16_t)v;
    hi[i] = h;
    lo[i] = (bf16_t)(v - (float)h);
  }
}
__global__ void k_bias(const float* __restrict__ a, const float* __restrict__ b,
                       float* __restrict__ d, int n) {
  int i = blockIdx.x * 256 + threadIdx.x;
  if (i < n) d[i] = a[i] + b[i];
}
__global__ void k_fc(const bf16_t* __restrict__ hf, const bf16_t* __restrict__ hb,
                     const float* __restrict__ fw, const float* __restrict__ fb,
                     float* __restrict__ out) {
  int b = threadIdx.x;
  float s = fb[0];
  const bf16_t* pf = hf + (size_t)b * H_SZ;
  const bf16_t* pb = hb + (size_t)b * H_SZ;
  for (int j = 0; j < H_SZ; ++j) s += fw[j] * (float)pf[j];
  for (int j = 0; j < H_SZ; ++j) s += fw[H_SZ + j] * (float)pb[j];
  out[b] = s;
}

extern "C" void kernel_launch(void* const* d_in, const int* in_sizes, int n_in,
                              void* d_out, int out_size, void* d_ws, size_t ws_size,
                              hipStream_t stream) {
  (void)in_sizes; (void)n_in; (void)out_size; (void)ws_size;
  const float* x      = (const float*)d_in[0];
  const float* wih[4] = {(const float*)d_in[1], (const float*)d_in[5],
                         (const float*)d_in[9], (const float*)d_in[13]};
  const float* whh[4] = {(const float*)d_in[2], (const float*)d_in[6],
                         (const float*)d_in[10], (const float*)d_in[14]};
  const float* bih[4] = {(const float*)d_in[3], (const float*)d_in[7],
                         (const float*)d_in[11], (const float*)d_in[15]};
  const float* bhh[4] = {(const float*)d_in[4], (const float*)d_in[8],
                         (const float*)d_in[12], (const float*)d_in[16]};
  const float* fcw = (const float*)d_in[17];
  const float* fcb = (const float*)d_in[18];
  float* out = (float*)d_out;

  char* p = (char*)d_ws;
  auto take = [&](size_t bytes) { char* r = p; p += (bytes + 255) & ~(size_t)255; return r; };
  const int KinL[4] = {I_SZ, I_SZ, 512, 512};  // l0f, l0b, l1f, l1b
  bf16_t* wihb[4]; bf16_t* whhhi[3]; bf16_t* whhlo[3]; float* biasc[4];
  for (int k = 0; k < 4; ++k) {
    wihb[k] = (bf16_t*)take((size_t)1024 * KinL[k] * 2);
    biasc[k] = (float*)take(1024 * 4);
  }
  for (int k = 0; k < 3; ++k) {  // l1-bwd single step needs no whh
    whhhi[k] = (bf16_t*)take((size_t)1024 * 256 * 2);
    whhlo[k] = (bf16_t*)take((size_t)1024 * 256 * 2);
  }
  bf16_t* h0  = (bf16_t*)take((size_t)T_SZ * B_SZ * 512 * 2);  // 128 MiB
  bf16_t* h1f = (bf16_t*)take((size_t)B_SZ * H_SZ * 2);
  bf16_t* h1b = (bf16_t*)take((size_t)B_SZ * H_SZ * 2);

  for (int k = 0; k < 4; ++k) {
    int n = 1024 * KinL[k];
    k_cvt<<<dim3((n + 255) / 256), 256, 0, stream>>>(wih[k], wihb[k], n);
    k_bias<<<dim3(4), 256, 0, stream>>>(bih[k], bhh[k], biasc[k], 1024);
    if (k < 3)
      k_split<<<dim3(1024), 256, 0, stream>>>(whh[k], whhhi[k], whhlo[k], 1024 * 256);
  }

  l0_scan<<<dim3(16, 2), 1024, 0, stream>>>(
      x, wihb[0], whhhi[0], whhlo[0], biasc[0],
         wihb[1], whhhi[1], whhlo[1], biasc[1], h0);

  l1_scan<<<dim3(16, 2), 1024, 0, stream>>>(
      h0, wihb[2], whhhi[2], whhlo[2], biasc[2],
          wihb[3], biasc[3], h1f, h1b);

  k_fc<<<dim3(1), 256, 0, stream>>>(h1f, h1b, fcw, fcb, out);
}

// Round 3
// 30092.914 us; speedup vs baseline: 1.4770x; 1.4770x over previous
//
#include <hip/hip_runtime.h>

typedef __bf16 bf16_t;
typedef bf16_t bf16x8 __attribute__((ext_vector_type(8)));
typedef bf16_t bf16x4 __attribute__((ext_vector_type(4)));
typedef float f32x4 __attribute__((ext_vector_type(4)));

#define B_SZ 256
#define T_SZ 512
#define H_SZ 256
#define SCOPE_AGENT __HIP_MEMORY_SCOPE_AGENT

__device__ __forceinline__ float sigm(float x) { return 1.f / (1.f + __expf(-x)); }
__device__ __forceinline__ float tanhx(float x) {
  x = fminf(fmaxf(x, -15.f), 15.f);
  float e = __expf(-2.f * x);
  return (1.f - e) / (1.f + e);
}
__device__ __forceinline__ uint32_t pack_bf16x2(float a, float b) {
  union { bf16_t h[2]; uint32_t u; } v;
  v.h[0] = (bf16_t)a; v.h[1] = (bf16_t)b; return v.u;
}
#define MFMA(a, b, c) __builtin_amdgcn_mfma_f32_16x16x32_bf16((a), (b), (c), 0, 0, 0)

// ---------------------------------------------------------------------------
// Layer 0 scan. 256 blocks = 2 dir x 16 bt x 8 ct, 256 threads (4 waves).
// Block owns 16 batch rows x 32 h-cols. Weights (wih bf16 + whh hi/lo) are
// REGISTER-RESIDENT per lane (144 VGPRs) -- zero per-step weight traffic.
// Per step: input-proj MFMAs issue BEFORE the flag spin (hides L3 latency),
// then 8 sibling col-blocks exchange h slices through global + LDS stage.
// Sync: per-(dir,bt,step) agent-scope arrival counter; relaxed poll +
// one acquire (buffer_inv) on success; producers threadfence (wbl2) before
// arriving. Deadlock-free: grid <= resident capacity.
// ---------------------------------------------------------------------------
__global__ __launch_bounds__(256, 1) void l0_scan(
    const bf16_t* __restrict__ xbf,
    const bf16_t* __restrict__ wih_f, const bf16_t* __restrict__ whhhi_f,
    const bf16_t* __restrict__ whhlo_f, const float* __restrict__ bias_f,
    const bf16_t* __restrict__ wih_b, const bf16_t* __restrict__ whhhi_b,
    const bf16_t* __restrict__ whhlo_b, const float* __restrict__ bias_b,
    bf16_t* __restrict__ h0, bf16_t* __restrict__ hg0, uint32_t* __restrict__ flags0) {
  const int id = blockIdx.x;
  const int dir = id >> 7, bt = (id >> 3) & 15, ct = id & 7;
  const bf16_t* __restrict__ wih  = dir ? wih_b : wih_f;
  const bf16_t* __restrict__ whhh = dir ? whhhi_b : whhhi_f;
  const bf16_t* __restrict__ whhl = dir ? whhlo_b : whhlo_f;
  const float*  __restrict__ bias = dir ? bias_b : bias_f;
  uint32_t* flag = flags0 + (size_t)(dir * 16 + bt) * 520;
  bf16_t*   hg   = hg0 + (size_t)(dir * 16 + bt) * 2 * 4096;  // [buf][16][256]

  const int tid = threadIdx.x;
  const int lane = tid & 63, wv = tid >> 6, l15 = lane & 63 & 15, quad = (tid & 63) >> 4;
  const int b0 = bt * 16;

  __shared__ bf16_t hbl[16][264];   // staged h_s (stride 528B: 16B-aligned, 2-way banks)
  __shared__ float  gl[16][132];    // gate pre-acts

  // ---- load register-resident weight fragments (once) ----
  bf16x8 wfi[2][2], wfh[2][8], wfl[2][8];
#pragma unroll
  for (int p = 0; p < 2; ++p) {
    const int n = wv * 2 + p;            // N-tile 0..7
    const int gc = n * 16 + l15;         // gate-col 0..127
    const int row = (gc >> 5) * H_SZ + ct * 32 + (gc & 31);
#pragma unroll
    for (int kt = 0; kt < 2; ++kt)
      wfi[p][kt] = *(const bf16x8*)(wih + (size_t)row * 64 + kt * 32 + quad * 8);
#pragma unroll
    for (int kt = 0; kt < 8; ++kt) {
      wfh[p][kt] = *(const bf16x8*)(whhh + (size_t)row * H_SZ + kt * 32 + quad * 8);
      wfl[p][kt] = *(const bf16x8*)(whhl + (size_t)row * H_SZ + kt * 32 + quad * 8);
    }
  }
  // epilogue ownership: thread t -> (row = t>>4, cols 2*(t&15)+{0,1})
  const int erow = tid >> 4, ecol = 2 * (tid & 15);
  const int gj = ct * 32 + ecol;
  float bia[4][2];
#pragma unroll
  for (int g = 0; g < 4; ++g) {
    bia[g][0] = bias[g * H_SZ + gj];
    bia[g][1] = bias[g * H_SZ + gj + 1];
  }
  float2 c2 = {0.f, 0.f};
  const bf16_t* xrow = xbf + (size_t)(b0 + l15) * T_SZ * 64;

  for (int s = 0; s < T_SZ; ++s) {
    const int t = dir ? (T_SZ - 1 - s) : s;
    // ---- input projection (independent of recurrence -> before spin) ----
    f32x4 acc0 = {0.f, 0.f, 0.f, 0.f}, acc1 = {0.f, 0.f, 0.f, 0.f};
#pragma unroll
    for (int kt = 0; kt < 2; ++kt) {
      bf16x8 xa = *(const bf16x8*)(xrow + t * 64 + kt * 32 + quad * 8);
      acc0 = MFMA(xa, wfi[0][kt], acc0);
      acc1 = MFMA(xa, wfi[1][kt], acc1);
    }
    // ---- wait for all 8 col-blocks' h_s slices ----
    if (s > 0 && tid == 0) {
      while (__hip_atomic_load(flag + s, __ATOMIC_RELAXED, SCOPE_AGENT) < 8u) {}
      (void)__hip_atomic_load(flag + s, __ATOMIC_ACQUIRE, SCOPE_AGENT);
    }
    __syncthreads();
    // ---- stage h_s into LDS (256 th x 32 B) ----
    {
      const bf16_t* src = hg + (size_t)(s & 1) * 4096;
      const int r = tid >> 4, cc = (tid & 15) * 16;
      *(bf16x8*)&hbl[r][cc]     = *(const bf16x8*)(src + r * H_SZ + cc);
      *(bf16x8*)&hbl[r][cc + 8] = *(const bf16x8*)(src + r * H_SZ + cc + 8);
    }
    __syncthreads();
    // ---- recurrent MFMAs (weights in registers, A from LDS) ----
#pragma unroll
    for (int kt = 0; kt < 8; ++kt) {
      bf16x8 ha = *(const bf16x8*)&hbl[l15][kt * 32 + quad * 8];
      acc0 = MFMA(ha, wfh[0][kt], acc0);
      acc0 = MFMA(ha, wfl[0][kt], acc0);
      acc1 = MFMA(ha, wfh[1][kt], acc1);
      acc1 = MFMA(ha, wfl[1][kt], acc1);
    }
    // ---- gates -> LDS (C/D layout: col=lane&15, row=quad*4+r) ----
#pragma unroll
    for (int r = 0; r < 4; ++r) {
      gl[quad * 4 + r][(wv * 2 + 0) * 16 + l15] = acc0[r];
      gl[quad * 4 + r][(wv * 2 + 1) * 16 + l15] = acc1[r];
    }
    __syncthreads();
    // ---- lane-owned gate combine + h/c update ----
    {
      float hv[2];
#pragma unroll
      for (int u = 0; u < 2; ++u) {
        float iv = sigm(gl[erow][0 * 32 + ecol + u] + bia[0][u]);
        float fv = sigm(gl[erow][1 * 32 + ecol + u] + bia[1][u]);
        float gv = tanhx(gl[erow][2 * 32 + ecol + u] + bia[2][u]);
        float ov = sigm(gl[erow][3 * 32 + ecol + u] + bia[3][u]);
        float cp = u ? c2.y : c2.x;
        float cn = fv * cp + iv * gv;
        if (u) c2.y = cn; else c2.x = cn;
        hv[u] = ov * tanhx(cn);
      }
      uint32_t pk = pack_bf16x2(hv[0], hv[1]);
      *(uint32_t*)(hg + (size_t)((s + 1) & 1) * 4096 + erow * H_SZ + gj) = pk;
      *(uint32_t*)(h0 + ((size_t)t * B_SZ + b0 + erow) * 512 + dir * H_SZ + gj) = pk;
    }
    __threadfence();
    __syncthreads();
    if (tid == 0)
      __hip_atomic_fetch_add(flag + s + 1, 1u, __ATOMIC_RELEASE, SCOPE_AGENT);
  }
}

// ---------------------------------------------------------------------------
// Layer 1 forward scan. 128 blocks = 16 bt x 8 ct, 512 threads (8 waves).
// Wave owns 1 N-tile. Input h0[t] tile (16x512) LDS double-buffered,
// prefetched (no recurrence dependence). Same flag protocol, group=8.
// ---------------------------------------------------------------------------
__global__ __launch_bounds__(512, 2) void l1_scan(
    const bf16_t* __restrict__ h0,
    const bf16_t* __restrict__ wih, const bf16_t* __restrict__ whhh,
    const bf16_t* __restrict__ whhl, const float* __restrict__ bias,
    bf16_t* __restrict__ h1f, bf16_t* __restrict__ hg1, uint32_t* __restrict__ flags1) {
  const int bt = blockIdx.x >> 3, ct = blockIdx.x & 7;
  uint32_t* flag = flags1 + (size_t)bt * 520;
  bf16_t*   hg   = hg1 + (size_t)bt * 2 * 4096;

  const int tid = threadIdx.x;
  const int lane = tid & 63, wv = tid >> 6, l15 = lane & 15, quad = lane >> 4;
  const int b0 = bt * 16;

  __shared__ bf16_t ibl[2][16][520];  // h0[t] tiles (stride 1040B: 16B-aligned)
  __shared__ bf16_t hbl[16][264];
  __shared__ float  gl[16][132];

  // ---- register-resident weights: wave wv = N-tile wv ----
  const int gc = wv * 16 + l15;
  const int row = (gc >> 5) * H_SZ + ct * 32 + (gc & 31);
  bf16x8 wfi[16], wfh[8], wfl[8];
#pragma unroll
  for (int kt = 0; kt < 16; ++kt)
    wfi[kt] = *(const bf16x8*)(wih + (size_t)row * 512 + kt * 32 + quad * 8);
#pragma unroll
  for (int kt = 0; kt < 8; ++kt) {
    wfh[kt] = *(const bf16x8*)(whhh + (size_t)row * H_SZ + kt * 32 + quad * 8);
    wfl[kt] = *(const bf16x8*)(whhl + (size_t)row * H_SZ + kt * 32 + quad * 8);
  }
  const int et = tid & 255;
  const int erow = et >> 4, ecol = 2 * (et & 15);
  const int gj = ct * 32 + ecol;
  float bia[4][2];
#pragma unroll
  for (int g = 0; g < 4; ++g) {
    bia[g][0] = bias[g * H_SZ + gj];
    bia[g][1] = bias[g * H_SZ + gj + 1];
  }
  float2 c2 = {0.f, 0.f};

  // stage ibl[0] <- h0[0]
  {
    const int r = tid >> 5, cc = (tid & 31) * 16;
    const bf16_t* src = h0 + ((size_t)0 * B_SZ + b0 + r) * 512 + cc;
    *(bf16x8*)&ibl[0][r][cc]     = *(const bf16x8*)(src);
    *(bf16x8*)&ibl[0][r][cc + 8] = *(const bf16x8*)(src + 8);
  }
  __syncthreads();

  for (int s = 0; s < T_SZ; ++s) {
    const int cur = s & 1, nxt = cur ^ 1;
    // prefetch next input tile (available since l0 finished -> no dependence)
    if (s + 1 < T_SZ) {
      const int r = tid >> 5, cc = (tid & 31) * 16;
      const bf16_t* src = h0 + ((size_t)(s + 1) * B_SZ + b0 + r) * 512 + cc;
      *(bf16x8*)&ibl[nxt][r][cc]     = *(const bf16x8*)(src);
      *(bf16x8*)&ibl[nxt][r][cc + 8] = *(const bf16x8*)(src + 8);
    }
    // ---- input projection before spin ----
    f32x4 acc = {0.f, 0.f, 0.f, 0.f};
#pragma unroll
    for (int kt = 0; kt < 16; ++kt) {
      bf16x8 a = *(const bf16x8*)&ibl[cur][l15][kt * 32 + quad * 8];
      acc = MFMA(a, wfi[kt], acc);
    }
    if (s > 0 && tid == 0) {
      while (__hip_atomic_load(flag + s, __ATOMIC_RELAXED, SCOPE_AGENT) < 8u) {}
      (void)__hip_atomic_load(flag + s, __ATOMIC_ACQUIRE, SCOPE_AGENT);
    }
    __syncthreads();
    // stage h_s (512 th x 8 elems)
    {
      const bf16_t* src = hg + (size_t)(s & 1) * 4096;
      const int r = tid >> 5, cc = (tid & 31) * 8;
      *(bf16x8*)&hbl[r][cc] = *(const bf16x8*)(src + r * H_SZ + cc);
    }
    __syncthreads();
#pragma unroll
    for (int kt = 0; kt < 8; ++kt) {
      bf16x8 ha = *(const bf16x8*)&hbl[l15][kt * 32 + quad * 8];
      acc = MFMA(ha, wfh[kt], acc);
      acc = MFMA(ha, wfl[kt], acc);
    }
#pragma unroll
    for (int r = 0; r < 4; ++r) gl[quad * 4 + r][wv * 16 + l15] = acc[r];
    __syncthreads();
    if (tid < 256) {
      float hv[2];
#pragma unroll
      for (int u = 0; u < 2; ++u) {
        float iv = sigm(gl[erow][0 * 32 + ecol + u] + bia[0][u]);
        float fv = sigm(gl[erow][1 * 32 + ecol + u] + bia[1][u]);
        float gv = tanhx(gl[erow][2 * 32 + ecol + u] + bia[2][u]);
        float ov = sigm(gl[erow][3 * 32 + ecol + u] + bia[3][u]);
        float cp = u ? c2.y : c2.x;
        float cn = fv * cp + iv * gv;
        if (u) c2.y = cn; else c2.x = cn;
        hv[u] = ov * tanhx(cn);
      }
      uint32_t pk = pack_bf16x2(hv[0], hv[1]);
      *(uint32_t*)(hg + (size_t)((s + 1) & 1) * 4096 + erow * H_SZ + gj) = pk;
      if (s == T_SZ - 1)
        *(uint32_t*)(h1f + (size_t)(b0 + erow) * H_SZ + gj) = pk;
    }
    __threadfence();
    __syncthreads();
    if (tid == 0)
      __hip_atomic_fetch_add(flag + s + 1, 1u, __ATOMIC_RELEASE, SCOPE_AGENT);
  }
}

// ---------------------------------------------------------------------------
// Layer 1 reverse direction: output needs only t=T-1 = ONE step from zero
// state -> pure input projection + gate combine. 64 blocks x 256 threads.
// ---------------------------------------------------------------------------
__global__ __launch_bounds__(256) void l1b_step(
    const bf16_t* __restrict__ h0, const bf16_t* __restrict__ wih_r,
    const float* __restrict__ bias_r, bf16_t* __restrict__ h1b) {
  const int bt = blockIdx.x >> 2, ct = blockIdx.x & 3;
  const int tid = threadIdx.x, lane = tid & 63, wv = tid >> 6;
  const int l15 = lane & 15, quad = lane >> 4;
  const int c0 = ct * 64 + wv * 16;
  const bf16_t* arow = h0 + ((size_t)(T_SZ - 1) * B_SZ + bt * 16 + l15) * 512;
  f32x4 acc[4] = {{0,0,0,0},{0,0,0,0},{0,0,0,0},{0,0,0,0}};
#pragma unroll 4
  for (int kt = 0; kt < 16; ++kt) {
    bf16x8 a = *(const bf16x8*)(arow + kt * 32 + quad * 8);
#pragma unroll
    for (int g = 0; g < 4; ++g) {
      bf16x8 w = *(const bf16x8*)(wih_r + (size_t)(g * H_SZ + c0 + l15) * 512 + kt * 32 + quad * 8);
      acc[g] = MFMA(a, w, acc[g]);
    }
  }
  const int j = c0 + l15;
  const float bi = bias_r[j], bg = bias_r[2 * H_SZ + j], bo = bias_r[3 * H_SZ + j];
#pragma unroll
  for (int r = 0; r < 4; ++r) {
    const int row = bt * 16 + quad * 4 + r;
    float iv = sigm(acc[0][r] + bi);
    float gv = tanhx(acc[2][r] + bg);
    float ov = sigm(acc[3][r] + bo);
    float cn = iv * gv;  // f*0 + i*g
    h1b[(size_t)row * H_SZ + j] = (bf16_t)(ov * tanhx(cn));
  }
}

// ---------------------------------------------------------------------------
// prep + head
// ---------------------------------------------------------------------------
__global__ void k_cvt4(const float* __restrict__ s, bf16_t* __restrict__ d, int n4) {
  int i = blockIdx.x * 256 + threadIdx.x;
  if (i < n4) {
    float4 v = ((const float4*)s)[i];
    bf16x4 o; o[0] = (bf16_t)v.x; o[1] = (bf16_t)v.y; o[2] = (bf16_t)v.z; o[3] = (bf16_t)v.w;
    ((bf16x4*)d)[i] = o;
  }
}
__global__ void k_split(const float* __restrict__ s, bf16_t* __restrict__ hi,
                        bf16_t* __restrict__ lo, int n) {
  int i = blockIdx.x * 256 + threadIdx.x;
  if (i < n) {
    float v = s[i];
    bf16_t h = (bf16_t)v;
    hi[i] = h;
    lo[i] = (bf16_t)(v - (float)h);
  }
}
__global__ void k_bias(const float* __restrict__ a, const float* __restrict__ b,
                       float* __restrict__ d, int n) {
  int i = blockIdx.x * 256 + threadIdx.x;
  if (i < n) d[i] = a[i] + b[i];
}
__global__ void k_zero32(uint32_t* __restrict__ p, int n) {
  int i = blockIdx.x * 256 + threadIdx.x;
  if (i < n) p[i] = 0u;
}
__global__ void k_fc(const bf16_t* __restrict__ hf, const bf16_t* __restrict__ hb,
                     const float* __restrict__ fw, const float* __restrict__ fb,
                     float* __restrict__ out) {
  int b = threadIdx.x;
  float s = fb[0];
  const bf16_t* pf = hf + (size_t)b * H_SZ;
  const bf16_t* pb = hb + (size_t)b * H_SZ;
  for (int j = 0; j < H_SZ; ++j) s += fw[j] * (float)pf[j];
  for (int j = 0; j < H_SZ; ++j) s += fw[H_SZ + j] * (float)pb[j];
  out[b] = s;
}

extern "C" void kernel_launch(void* const* d_in, const int* in_sizes, int n_in,
                              void* d_out, int out_size, void* d_ws, size_t ws_size,
                              hipStream_t stream) {
  (void)in_sizes; (void)n_in; (void)out_size; (void)ws_size;
  const float* x      = (const float*)d_in[0];
  const float* wih[4] = {(const float*)d_in[1], (const float*)d_in[5],
                         (const float*)d_in[9], (const float*)d_in[13]};
  const float* whh[4] = {(const float*)d_in[2], (const float*)d_in[6],
                         (const float*)d_in[10], (const float*)d_in[14]};
  const float* bih[4] = {(const float*)d_in[3], (const float*)d_in[7],
                         (const float*)d_in[11], (const float*)d_in[15]};
  const float* bhh[4] = {(const float*)d_in[4], (const float*)d_in[8],
                         (const float*)d_in[12], (const float*)d_in[16]};
  const float* fcw = (const float*)d_in[17];
  const float* fcb = (const float*)d_in[18];
  float* out = (float*)d_out;

  char* p = (char*)d_ws;
  auto take = [&](size_t bytes) { char* r = p; p += (bytes + 255) & ~(size_t)255; return r; };
  const int KinL[4] = {64, 64, 512, 512};  // l0f, l0b, l1f, l1r
  bf16_t* wihb[4]; float* biasc[4]; bf16_t* whhhi[3]; bf16_t* whhlo[3];
  for (int k = 0; k < 4; ++k) {
    wihb[k]  = (bf16_t*)take((size_t)1024 * KinL[k] * 2);
    biasc[k] = (float*)take(1024 * 4);
  }
  for (int k = 0; k < 3; ++k) {  // l0f, l0b, l1f (l1r single step needs no whh)
    whhhi[k] = (bf16_t*)take((size_t)1024 * 256 * 2);
    whhlo[k] = (bf16_t*)take((size_t)1024 * 256 * 2);
  }
  bf16_t* xbf = (bf16_t*)take((size_t)B_SZ * T_SZ * 64 * 2);       // 16 MiB
  bf16_t* h0  = (bf16_t*)take((size_t)T_SZ * B_SZ * 512 * 2);      // 128 MiB
  bf16_t* h1f = (bf16_t*)take((size_t)B_SZ * H_SZ * 2);
  bf16_t* h1b = (bf16_t*)take((size_t)B_SZ * H_SZ * 2);
  char* zbeg = p;
  bf16_t*   hg0    = (bf16_t*)take((size_t)32 * 2 * 4096 * 2);     // 512 KiB
  bf16_t*   hg1    = (bf16_t*)take((size_t)16 * 2 * 4096 * 2);     // 256 KiB
  uint32_t* flags0 = (uint32_t*)take((size_t)32 * 520 * 4);
  uint32_t* flags1 = (uint32_t*)take((size_t)16 * 520 * 4);
  char* zend = p;

  // ---- prep ----
  k_cvt4<<<dim3(8192), 256, 0, stream>>>(x, xbf, (B_SZ * T_SZ * 64) / 4);
  for (int k = 0; k < 4; ++k) {
    k_cvt4<<<dim3((1024 * KinL[k] / 4 + 255) / 256), 256, 0, stream>>>(
        wih[k], wihb[k], 1024 * KinL[k] / 4);
    k_bias<<<dim3(4), 256, 0, stream>>>(bih[k], bhh[k], biasc[k], 1024);
  }
  for (int k = 0; k < 3; ++k)
    k_split<<<dim3(1024), 256, 0, stream>>>(whh[k], whhhi[k], whhlo[k], 1024 * 256);
  {
    int zn = (int)((zend - zbeg) / 4);
    k_zero32<<<dim3((zn + 255) / 256), 256, 0, stream>>>((uint32_t*)zbeg, zn);
  }

  // ---- scans ----
  l0_scan<<<dim3(256), 256, 0, stream>>>(
      xbf, wihb[0], whhhi[0], whhlo[0], biasc[0],
           wihb[1], whhhi[1], whhlo[1], biasc[1], h0, hg0, flags0);
  l1_scan<<<dim3(128), 512, 0, stream>>>(
      h0, wihb[2], whhhi[2], whhlo[2], biasc[2], h1f, hg1, flags1);
  l1b_step<<<dim3(64), 256, 0, stream>>>(h0, wihb[3], biasc[3], h1b);

  k_fc<<<dim3(1), 256, 0, stream>>>(h1f, h1b, fcw, fcb, out);
}

// Round 4
// 3010.445 us; speedup vs baseline: 14.7644x; 9.9962x over previous
//
#include <hip/hip_runtime.h>

typedef __bf16 bf16_t;
typedef bf16_t bf16x8 __attribute__((ext_vector_type(8)));
typedef bf16_t bf16x4 __attribute__((ext_vector_type(4)));
typedef float f32x4 __attribute__((ext_vector_type(4)));

#define B_SZ 256
#define T_SZ 512
#define H_SZ 256
#define SCOPE_AGENT __HIP_MEMORY_SCOPE_AGENT
#define SLOT_STRIDE 16  // uint32s -> 64B line per slot

__device__ __forceinline__ float sigm(float x) { return 1.f / (1.f + __expf(-x)); }
__device__ __forceinline__ float tanhx(float x) {
  x = fminf(fmaxf(x, -15.f), 15.f);
  float e = __expf(-2.f * x);
  return (1.f - e) / (1.f + e);
}
__device__ __forceinline__ uint32_t pack_bf16x2(float a, float b) {
  union { bf16_t h[2]; uint32_t u; } v;
  v.h[0] = (bf16_t)a; v.h[1] = (bf16_t)b; return v.u;
}
// Coherent-path (agent-scope, relaxed) ops: sc1 write-through stores and
// coherence-point loads. No fences, no cache-wide wbl2/inv anywhere.
__device__ __forceinline__ void st32_agent(uint32_t* p, uint32_t v) {
  __hip_atomic_store(p, v, __ATOMIC_RELAXED, SCOPE_AGENT);
}
__device__ __forceinline__ uint32_t ld32_agent(const uint32_t* p) {
  return __hip_atomic_load(p, __ATOMIC_RELAXED, SCOPE_AGENT);
}
__device__ __forceinline__ uint64_t ld64_agent(const uint64_t* p) {
  return __hip_atomic_load(p, __ATOMIC_RELAXED, SCOPE_AGENT);
}
#define MFMA(a, b, c) __builtin_amdgcn_mfma_f32_16x16x32_bf16((a), (b), (c), 0, 0, 0)

// ---------------------------------------------------------------------------
// Layer 0 scan. 256 blocks = 2 dir x 16 bt x 8 ct, 256 threads (4 waves).
// Block owns 16 batch rows x 32 h-cols; weights register-resident.
// Per step: input-proj MFMAs issue before the spin; 8 sibling col-blocks
// exchange h slices via agent-scope write-through stores + per-producer
// slot counters (64B apart). Safety: producers' data stores COMPLETE
// (vmcnt drain at __syncthreads) before the slot store issues, so a
// consumer that observes slot>=s sees the data at the coherence point.
// ---------------------------------------------------------------------------
__global__ __launch_bounds__(256, 1) void l0_scan(
    const bf16_t* __restrict__ xbf,
    const bf16_t* __restrict__ wih_f, const bf16_t* __restrict__ whhhi_f,
    const bf16_t* __restrict__ whhlo_f, const float* __restrict__ bias_f,
    const bf16_t* __restrict__ wih_b, const bf16_t* __restrict__ whhhi_b,
    const bf16_t* __restrict__ whhlo_b, const float* __restrict__ bias_b,
    bf16_t* __restrict__ h0, bf16_t* __restrict__ hg0, uint32_t* __restrict__ slots0) {
  const int id = blockIdx.x;
  const int dir = id >> 7, bt = (id >> 3) & 15, ct = id & 7;
  const bf16_t* __restrict__ wih  = dir ? wih_b : wih_f;
  const bf16_t* __restrict__ whhh = dir ? whhhi_b : whhhi_f;
  const bf16_t* __restrict__ whhl = dir ? whhlo_b : whhlo_f;
  const float*  __restrict__ bias = dir ? bias_b : bias_f;
  uint32_t* slots  = slots0 + (size_t)(dir * 16 + bt) * 8 * SLOT_STRIDE;
  uint32_t* myslot = slots + ct * SLOT_STRIDE;
  bf16_t*   hg     = hg0 + (size_t)(dir * 16 + bt) * 2 * 4096;  // [buf][16][256]

  const int tid = threadIdx.x;
  const int lane = tid & 63, wv = tid >> 6, l15 = lane & 15, quad = lane >> 4;
  const int b0 = bt * 16;

  __shared__ bf16_t hbl[16][264];   // staged h_s (528B stride: 16B-aligned)
  __shared__ float  gl[16][132];    // gate pre-acts

  // ---- register-resident weight fragments (loaded once) ----
  bf16x8 wfi[2][2], wfh[2][8], wfl[2][8];
#pragma unroll
  for (int p = 0; p < 2; ++p) {
    const int gc = (wv * 2 + p) * 16 + l15;          // gate-col 0..127
    const int row = (gc >> 5) * H_SZ + ct * 32 + (gc & 31);
#pragma unroll
    for (int kt = 0; kt < 2; ++kt)
      wfi[p][kt] = *(const bf16x8*)(wih + (size_t)row * 64 + kt * 32 + quad * 8);
#pragma unroll
    for (int kt = 0; kt < 8; ++kt) {
      wfh[p][kt] = *(const bf16x8*)(whhh + (size_t)row * H_SZ + kt * 32 + quad * 8);
      wfl[p][kt] = *(const bf16x8*)(whhl + (size_t)row * H_SZ + kt * 32 + quad * 8);
    }
  }
  const int erow = tid >> 4, ecol = 2 * (tid & 15);
  const int gj = ct * 32 + ecol;
  float bia[4][2];
#pragma unroll
  for (int g = 0; g < 4; ++g) {
    bia[g][0] = bias[g * H_SZ + gj];
    bia[g][1] = bias[g * H_SZ + gj + 1];
  }
  float2 c2 = {0.f, 0.f};
  const bf16_t* xrow = xbf + (size_t)(b0 + l15) * T_SZ * 64;

  for (int s = 0; s < T_SZ; ++s) {
    const int t = dir ? (T_SZ - 1 - s) : s;
    // ---- input projection (independent of recurrence -> before spin) ----
    f32x4 acc0 = {0.f, 0.f, 0.f, 0.f}, acc1 = {0.f, 0.f, 0.f, 0.f};
#pragma unroll
    for (int kt = 0; kt < 2; ++kt) {
      bf16x8 xa = *(const bf16x8*)(xrow + t * 64 + kt * 32 + quad * 8);
      acc0 = MFMA(xa, wfi[0][kt], acc0);
      acc1 = MFMA(xa, wfi[1][kt], acc1);
    }
    if (s == 0) {
      // h_0 = 0: zero the LDS stage directly, no global read
      for (int i = tid; i < 16 * 264 / 2; i += 256) ((uint32_t*)hbl)[i] = 0u;
    } else {
      // ---- spin: lanes 0..7 of wave 0 poll the 8 producer slots ----
      if (wv == 0) {
        const uint32_t tgt = (uint32_t)s;
        for (;;) {
          uint32_t v = (lane < 8) ? ld32_agent(slots + lane * SLOT_STRIDE) : tgt;
          if (__all((int)(v >= tgt))) break;
        }
      }
      __syncthreads();
      // ---- stage h_s into LDS via coherent 8B loads ----
      const uint64_t* src = (const uint64_t*)(hg + (size_t)(s & 1) * 4096);
#pragma unroll
      for (int k = 0; k < 4; ++k) {
        const int idx = tid + k * 256;          // 1024 x 8B = 16x256 bf16
        uint64_t v = ld64_agent(src + idx);
        *(uint64_t*)&hbl[idx >> 6][(idx & 63) * 4] = v;
      }
    }
    __syncthreads();
    // ---- recurrent MFMAs (weights in registers, A from LDS) ----
#pragma unroll
    for (int kt = 0; kt < 8; ++kt) {
      bf16x8 ha = *(const bf16x8*)&hbl[l15][kt * 32 + quad * 8];
      acc0 = MFMA(ha, wfh[0][kt], acc0);
      acc0 = MFMA(ha, wfl[0][kt], acc0);
      acc1 = MFMA(ha, wfh[1][kt], acc1);
      acc1 = MFMA(ha, wfl[1][kt], acc1);
    }
    // ---- gates -> LDS (C/D layout: col=lane&15, row=quad*4+r) ----
#pragma unroll
    for (int r = 0; r < 4; ++r) {
      gl[quad * 4 + r][(wv * 2 + 0) * 16 + l15] = acc0[r];
      gl[quad * 4 + r][(wv * 2 + 1) * 16 + l15] = acc1[r];
    }
    __syncthreads();
    // ---- lane-owned gate combine + h/c update ----
    {
      float hv[2];
#pragma unroll
      for (int u = 0; u < 2; ++u) {
        float iv = sigm(gl[erow][0 * 32 + ecol + u] + bia[0][u]);
        float fv = sigm(gl[erow][1 * 32 + ecol + u] + bia[1][u]);
        float gv = tanhx(gl[erow][2 * 32 + ecol + u] + bia[2][u]);
        float ov = sigm(gl[erow][3 * 32 + ecol + u] + bia[3][u]);
        float cp = u ? c2.y : c2.x;
        float cn = fv * cp + iv * gv;
        if (u) c2.y = cn; else c2.x = cn;
        hv[u] = ov * tanhx(cn);
      }
      uint32_t pk = pack_bf16x2(hv[0], hv[1]);
      st32_agent((uint32_t*)(hg + (size_t)((s + 1) & 1) * 4096 + erow * H_SZ + gj), pk);
      *(uint32_t*)(h0 + ((size_t)t * B_SZ + b0 + erow) * 512 + dir * H_SZ + gj) = pk;
    }
    __syncthreads();                       // implicit vmcnt(0): data stores done
    if (tid == 0) st32_agent(myslot, (uint32_t)(s + 1));
  }
}

// ---------------------------------------------------------------------------
// Layer 1 forward scan. 128 blocks = 16 bt x 8 ct, 512 threads (8 waves).
// Input h0[t] tile LDS double-buffered via NORMAL cached loads (no
// invalidation now -> stays warm in L2). Same slot protocol.
// ---------------------------------------------------------------------------
__global__ __launch_bounds__(512, 2) void l1_scan(
    const bf16_t* __restrict__ h0,
    const bf16_t* __restrict__ wih, const bf16_t* __restrict__ whhh,
    const bf16_t* __restrict__ whhl, const float* __restrict__ bias,
    bf16_t* __restrict__ h1f, bf16_t* __restrict__ hg1, uint32_t* __restrict__ slots1) {
  const int bt = blockIdx.x >> 3, ct = blockIdx.x & 7;
  uint32_t* slots  = slots1 + (size_t)bt * 8 * SLOT_STRIDE;
  uint32_t* myslot = slots + ct * SLOT_STRIDE;
  bf16_t*   hg     = hg1 + (size_t)bt * 2 * 4096;

  const int tid = threadIdx.x;
  const int lane = tid & 63, wv = tid >> 6, l15 = lane & 15, quad = lane >> 4;
  const int b0 = bt * 16;

  __shared__ bf16_t ibl[2][16][520];
  __shared__ bf16_t hbl[16][264];
  __shared__ float  gl[16][132];

  const int gc = wv * 16 + l15;
  const int row = (gc >> 5) * H_SZ + ct * 32 + (gc & 31);
  bf16x8 wfi[16], wfh[8], wfl[8];
#pragma unroll
  for (int kt = 0; kt < 16; ++kt)
    wfi[kt] = *(const bf16x8*)(wih + (size_t)row * 512 + kt * 32 + quad * 8);
#pragma unroll
  for (int kt = 0; kt < 8; ++kt) {
    wfh[kt] = *(const bf16x8*)(whhh + (size_t)row * H_SZ + kt * 32 + quad * 8);
    wfl[kt] = *(const bf16x8*)(whhl + (size_t)row * H_SZ + kt * 32 + quad * 8);
  }
  const int et = tid & 255;
  const int erow = et >> 4, ecol = 2 * (et & 15);
  const int gj = ct * 32 + ecol;
  float bia[4][2];
#pragma unroll
  for (int g = 0; g < 4; ++g) {
    bia[g][0] = bias[g * H_SZ + gj];
    bia[g][1] = bias[g * H_SZ + gj + 1];
  }
  float2 c2 = {0.f, 0.f};

  // stage ibl[0] <- h0[t=0]
  {
    const int r = tid >> 5, cc = (tid & 31) * 16;
    const bf16_t* src = h0 + ((size_t)(b0 + r)) * 512 + cc;
    *(bf16x8*)&ibl[0][r][cc]     = *(const bf16x8*)(src);
    *(bf16x8*)&ibl[0][r][cc + 8] = *(const bf16x8*)(src + 8);
  }
  __syncthreads();

  for (int s = 0; s < T_SZ; ++s) {
    const int cur = s & 1, nxt = cur ^ 1;
    if (s + 1 < T_SZ) {  // prefetch next input tile (cached, no dependence)
      const int r = tid >> 5, cc = (tid & 31) * 16;
      const bf16_t* src = h0 + ((size_t)(s + 1) * B_SZ + b0 + r) * 512 + cc;
      *(bf16x8*)&ibl[nxt][r][cc]     = *(const bf16x8*)(src);
      *(bf16x8*)&ibl[nxt][r][cc + 8] = *(const bf16x8*)(src + 8);
    }
    f32x4 acc = {0.f, 0.f, 0.f, 0.f};
#pragma unroll
    for (int kt = 0; kt < 16; ++kt) {
      bf16x8 a = *(const bf16x8*)&ibl[cur][l15][kt * 32 + quad * 8];
      acc = MFMA(a, wfi[kt], acc);
    }
    if (s == 0) {
      for (int i = tid; i < 16 * 264 / 2; i += 512) ((uint32_t*)hbl)[i] = 0u;
    } else {
      if (wv == 0) {
        const uint32_t tgt = (uint32_t)s;
        for (;;) {
          uint32_t v = (lane < 8) ? ld32_agent(slots + lane * SLOT_STRIDE) : tgt;
          if (__all((int)(v >= tgt))) break;
        }
      }
      __syncthreads();
      const uint64_t* src = (const uint64_t*)(hg + (size_t)(s & 1) * 4096);
#pragma unroll
      for (int k = 0; k < 2; ++k) {
        const int idx = tid + k * 512;
        uint64_t v = ld64_agent(src + idx);
        *(uint64_t*)&hbl[idx >> 6][(idx & 63) * 4] = v;
      }
    }
    __syncthreads();
#pragma unroll
    for (int kt = 0; kt < 8; ++kt) {
      bf16x8 ha = *(const bf16x8*)&hbl[l15][kt * 32 + quad * 8];
      acc = MFMA(ha, wfh[kt], acc);
      acc = MFMA(ha, wfl[kt], acc);
    }
#pragma unroll
    for (int r = 0; r < 4; ++r) gl[quad * 4 + r][wv * 16 + l15] = acc[r];
    __syncthreads();
    if (tid < 256) {
      float hv[2];
#pragma unroll
      for (int u = 0; u < 2; ++u) {
        float iv = sigm(gl[erow][0 * 32 + ecol + u] + bia[0][u]);
        float fv = sigm(gl[erow][1 * 32 + ecol + u] + bia[1][u]);
        float gv = tanhx(gl[erow][2 * 32 + ecol + u] + bia[2][u]);
        float ov = sigm(gl[erow][3 * 32 + ecol + u] + bia[3][u]);
        float cp = u ? c2.y : c2.x;
        float cn = fv * cp + iv * gv;
        if (u) c2.y = cn; else c2.x = cn;
        hv[u] = ov * tanhx(cn);
      }
      uint32_t pk = pack_bf16x2(hv[0], hv[1]);
      st32_agent((uint32_t*)(hg + (size_t)((s + 1) & 1) * 4096 + erow * H_SZ + gj), pk);
      if (s == T_SZ - 1)
        *(uint32_t*)(h1f + (size_t)(b0 + erow) * H_SZ + gj) = pk;
    }
    __syncthreads();
    if (tid == 0) st32_agent(myslot, (uint32_t)(s + 1));
  }
}

// ---------------------------------------------------------------------------
// Layer 1 reverse direction: output needs only t=T-1 = ONE step from zero
// state -> pure input projection + gate combine.
// ---------------------------------------------------------------------------
__global__ __launch_bounds__(256) void l1b_step(
    const bf16_t* __restrict__ h0, const bf16_t* __restrict__ wih_r,
    const float* __restrict__ bias_r, bf16_t* __restrict__ h1b) {
  const int bt = blockIdx.x >> 2, ct = blockIdx.x & 3;
  const int tid = threadIdx.x, lane = tid & 63, wv = tid >> 6;
  const int l15 = lane & 15, quad = lane >> 4;
  const int c0 = ct * 64 + wv * 16;
  const bf16_t* arow = h0 + ((size_t)(T_SZ - 1) * B_SZ + bt * 16 + l15) * 512;
  f32x4 acc[4] = {{0,0,0,0},{0,0,0,0},{0,0,0,0},{0,0,0,0}};
#pragma unroll 4
  for (int kt = 0; kt < 16; ++kt) {
    bf16x8 a = *(const bf16x8*)(arow + kt * 32 + quad * 8);
#pragma unroll
    for (int g = 0; g < 4; ++g) {
      bf16x8 w = *(const bf16x8*)(wih_r + (size_t)(g * H_SZ + c0 + l15) * 512 + kt * 32 + quad * 8);
      acc[g] = MFMA(a, w, acc[g]);
    }
  }
  const int j = c0 + l15;
  const float bi = bias_r[j], bg = bias_r[2 * H_SZ + j], bo = bias_r[3 * H_SZ + j];
#pragma unroll
  for (int r = 0; r < 4; ++r) {
    const int row = bt * 16 + quad * 4 + r;
    float iv = sigm(acc[0][r] + bi);
    float gv = tanhx(acc[2][r] + bg);
    float ov = sigm(acc[3][r] + bo);
    float cn = iv * gv;  // f*0 + i*g
    h1b[(size_t)row * H_SZ + j] = (bf16_t)(ov * tanhx(cn));
  }
}

// ---------------------------------------------------------------------------
// prep + head
// ---------------------------------------------------------------------------
__global__ void k_cvt4(const float* __restrict__ s, bf16_t* __restrict__ d, int n4) {
  int i = blockIdx.x * 256 + threadIdx.x;
  if (i < n4) {
    float4 v = ((const float4*)s)[i];
    bf16x4 o; o[0] = (bf16_t)v.x; o[1] = (bf16_t)v.y; o[2] = (bf16_t)v.z; o[3] = (bf16_t)v.w;
    ((bf16x4*)d)[i] = o;
  }
}
__global__ void k_split(const float* __restrict__ s, bf16_t* __restrict__ hi,
                        bf16_t* __restrict__ lo, int n) {
  int i = blockIdx.x * 256 + threadIdx.x;
  if (i < n) {
    float v = s[i];
    bf16_t h = (bf16_t)v;
    hi[i] = h;
    lo[i] = (bf16_t)(v - (float)h);
  }
}
__global__ void k_bias(const float* __restrict__ a, const float* __restrict__ b,
                       float* __restrict__ d, int n) {
  int i = blockIdx.x * 256 + threadIdx.x;
  if (i < n) d[i] = a[i] + b[i];
}
__global__ void k_zero32(uint32_t* __restrict__ p, int n) {
  int i = blockIdx.x * 256 + threadIdx.x;
  if (i < n) p[i] = 0u;
}
__global__ void k_fc(const bf16_t* __restrict__ hf, const bf16_t* __restrict__ hb,
                     const float* __restrict__ fw, const float* __restrict__ fb,
                     float* __restrict__ out) {
  int b = threadIdx.x;
  float s = fb[0];
  const bf16_t* pf = hf + (size_t)b * H_SZ;
  const bf16_t* pb = hb + (size_t)b * H_SZ;
  for (int j = 0; j < H_SZ; ++j) s += fw[j] * (float)pf[j];
  for (int j = 0; j < H_SZ; ++j) s += fw[H_SZ + j] * (float)pb[j];
  out[b] = s;
}

extern "C" void kernel_launch(void* const* d_in, const int* in_sizes, int n_in,
                              void* d_out, int out_size, void* d_ws, size_t ws_size,
                              hipStream_t stream) {
  (void)in_sizes; (void)n_in; (void)out_size; (void)ws_size;
  const float* x      = (const float*)d_in[0];
  const float* wih[4] = {(const float*)d_in[1], (const float*)d_in[5],
                         (const float*)d_in[9], (const float*)d_in[13]};
  const float* whh[4] = {(const float*)d_in[2], (const float*)d_in[6],
                         (const float*)d_in[10], (const float*)d_in[14]};
  const float* bih[4] = {(const float*)d_in[3], (const float*)d_in[7],
                         (const float*)d_in[11], (const float*)d_in[15]};
  const float* bhh[4] = {(const float*)d_in[4], (const float*)d_in[8],
                         (const float*)d_in[12], (const float*)d_in[16]};
  const float* fcw = (const float*)d_in[17];
  const float* fcb = (const float*)d_in[18];
  float* out = (float*)d_out;

  char* p = (char*)d_ws;
  auto take = [&](size_t bytes) { char* r = p; p += (bytes + 255) & ~(size_t)255; return r; };
  const int KinL[4] = {64, 64, 512, 512};  // l0f, l0b, l1f, l1r
  bf16_t* wihb[4]; float* biasc[4]; bf16_t* whhhi[3]; bf16_t* whhlo[3];
  for (int k = 0; k < 4; ++k) {
    wihb[k]  = (bf16_t*)take((size_t)1024 * KinL[k] * 2);
    biasc[k] = (float*)take(1024 * 4);
  }
  for (int k = 0; k < 3; ++k) {
    whhhi[k] = (bf16_t*)take((size_t)1024 * 256 * 2);
    whhlo[k] = (bf16_t*)take((size_t)1024 * 256 * 2);
  }
  bf16_t* xbf = (bf16_t*)take((size_t)B_SZ * T_SZ * 64 * 2);
  bf16_t* h0  = (bf16_t*)take((size_t)T_SZ * B_SZ * 512 * 2);   // 128 MiB
  bf16_t* h1f = (bf16_t*)take((size_t)B_SZ * H_SZ * 2);
  bf16_t* h1b = (bf16_t*)take((size_t)B_SZ * H_SZ * 2);
  bf16_t*   hg0    = (bf16_t*)take((size_t)32 * 2 * 4096 * 2);
  bf16_t*   hg1    = (bf16_t*)take((size_t)16 * 2 * 4096 * 2);
  char* zbeg = p;
  uint32_t* slots0 = (uint32_t*)take((size_t)32 * 8 * SLOT_STRIDE * 4);
  uint32_t* slots1 = (uint32_t*)take((size_t)16 * 8 * SLOT_STRIDE * 4);
  char* zend = p;

  // ---- prep ----
  k_cvt4<<<dim3(8192), 256, 0, stream>>>(x, xbf, (B_SZ * T_SZ * 64) / 4);
  for (int k = 0; k < 4; ++k) {
    k_cvt4<<<dim3((1024 * KinL[k] / 4 + 255) / 256), 256, 0, stream>>>(
        wih[k], wihb[k], 1024 * KinL[k] / 4);
    k_bias<<<dim3(4), 256, 0, stream>>>(bih[k], bhh[k], biasc[k], 1024);
  }
  for (int k = 0; k < 3; ++k)
    k_split<<<dim3(1024), 256, 0, stream>>>(whh[k], whhhi[k], whhlo[k], 1024 * 256);
  {
    int zn = (int)((zend - zbeg) / 4);   // slots MUST be zeroed (0xAA poison
    k_zero32<<<dim3((zn + 255) / 256), 256, 0, stream>>>((uint32_t*)zbeg, zn);
  }                                      //  would pass the spin instantly)

  // ---- scans ----
  l0_scan<<<dim3(256), 256, 0, stream>>>(
      xbf, wihb[0], whhhi[0], whhlo[0], biasc[0],
           wihb[1], whhhi[1], whhlo[1], biasc[1], h0, hg0, slots0);
  l1_scan<<<dim3(128), 512, 0, stream>>>(
      h0, wihb[2], whhhi[2], whhlo[2], biasc[2], h1f, hg1, slots1);
  l1b_step<<<dim3(64), 256, 0, stream>>>(h0, wihb[3], biasc[3], h1b);

  k_fc<<<dim3(1), 256, 0, stream>>>(h1f, h1b, fcw, fcb, out);
}

// Round 5
// 2275.562 us; speedup vs baseline: 19.5325x; 1.3229x over previous
//
#include <hip/hip_runtime.h>

typedef __bf16 bf16_t;
typedef bf16_t bf16x8 __attribute__((ext_vector_type(8)));
typedef bf16_t bf16x4 __attribute__((ext_vector_type(4)));
typedef float f32x4 __attribute__((ext_vector_type(4)));

#define B_SZ 256
#define T_SZ 512
#define H_SZ 256
#define SCOPE_AGENT __HIP_MEMORY_SCOPE_AGENT
#define SENT32 0x7FC17FC1u   // two bf16 NaNs; produced h is always finite

__device__ __forceinline__ float sigm(float x) { return 1.f / (1.f + __expf(-x)); }
__device__ __forceinline__ float tanhx(float x) {
  x = fminf(fmaxf(x, -15.f), 15.f);
  float e = __expf(-2.f * x);
  return (1.f - e) / (1.f + e);
}
__device__ __forceinline__ uint32_t pack_bf16x2(float a, float b) {
  union { bf16_t h[2]; uint32_t u; } v;
  v.h[0] = (bf16_t)a; v.h[1] = (bf16_t)b; return v.u;
}
__device__ __forceinline__ void st32_agent(uint32_t* p, uint32_t v) {
  __hip_atomic_store(p, v, __ATOMIC_RELAXED, SCOPE_AGENT);
}
__device__ __forceinline__ uint64_t ld64_agent(const uint64_t* p) {
  return __hip_atomic_load(p, __ATOMIC_RELAXED, SCOPE_AGENT);
}
__device__ __forceinline__ bool okv(uint64_t v) {
  return ((uint32_t)v != SENT32) & ((uint32_t)(v >> 32) != SENT32);
}
#define MFMA(a, b, c) __builtin_amdgcn_mfma_f32_16x16x32_bf16((a), (b), (c), 0, 0, 0)

// ---------------------------------------------------------------------------
// Layer 0 scan. 256 blocks = 2 dir x 16 bt x 8 ct, 256 threads (4 waves).
// Weights register-resident. FLAG-IN-DATA exchange: h0[t] itself is the
// per-step buffer (pre-filled with NaN sentinel). Producers write h via
// agent write-through; consumers poll exactly the words they consume
// (u32 granularity = one producer thread's atomic store). ONE fabric
// round-trip per step on the critical path; no slots, no fences.
// ---------------------------------------------------------------------------
__global__ __launch_bounds__(256, 1) void l0_scan(
    const bf16_t* __restrict__ xbf,
    const bf16_t* __restrict__ wih_f, const bf16_t* __restrict__ whhhi_f,
    const bf16_t* __restrict__ whhlo_f, const float* __restrict__ bias_f,
    const bf16_t* __restrict__ wih_b, const bf16_t* __restrict__ whhhi_b,
    const bf16_t* __restrict__ whhlo_b, const float* __restrict__ bias_b,
    bf16_t* __restrict__ h0) {
  const int id = blockIdx.x;
  const int dir = id >> 7, bt = (id >> 3) & 15, ct = id & 7;
  const bf16_t* __restrict__ wih  = dir ? wih_b : wih_f;
  const bf16_t* __restrict__ whhh = dir ? whhhi_b : whhhi_f;
  const bf16_t* __restrict__ whhl = dir ? whhlo_b : whhlo_f;
  const float*  __restrict__ bias = dir ? bias_b : bias_f;

  const int tid = threadIdx.x;
  const int lane = tid & 63, wv = tid >> 6, l15 = lane & 15, quad = lane >> 4;
  const int b0 = bt * 16;

  __shared__ bf16_t hbl[16][264];   // staged h_prev (528B stride, 16B-aligned)
  __shared__ float  gl[16][132];    // gate pre-acts

  // ---- register-resident weight fragments (loaded once) ----
  bf16x8 wfi[2][2], wfh[2][8], wfl[2][8];
#pragma unroll
  for (int p = 0; p < 2; ++p) {
    const int gc = (wv * 2 + p) * 16 + l15;          // gate-col 0..127
    const int row = (gc >> 5) * H_SZ + ct * 32 + (gc & 31);
#pragma unroll
    for (int kt = 0; kt < 2; ++kt)
      wfi[p][kt] = *(const bf16x8*)(wih + (size_t)row * 64 + kt * 32 + quad * 8);
#pragma unroll
    for (int kt = 0; kt < 8; ++kt) {
      wfh[p][kt] = *(const bf16x8*)(whhh + (size_t)row * H_SZ + kt * 32 + quad * 8);
      wfl[p][kt] = *(const bf16x8*)(whhl + (size_t)row * H_SZ + kt * 32 + quad * 8);
    }
  }
  const int erow = tid >> 4, ecol = 2 * (tid & 15);
  const int gj = ct * 32 + ecol;
  float bia[4][2];
#pragma unroll
  for (int g = 0; g < 4; ++g) {
    bia[g][0] = bias[g * H_SZ + gj];
    bia[g][1] = bias[g * H_SZ + gj + 1];
  }
  float2 c2 = {0.f, 0.f};
  const bf16_t* xrow = xbf + (size_t)(b0 + l15) * T_SZ * 64;
  // poll/stage ownership: row = tid>>4, u64-chunk (tid&15)*4 of the dir half
  const int prow = tid >> 4, pcq = (tid & 15) * 4;

  for (int s = 0; s < T_SZ; ++s) {
    const int t = dir ? (T_SZ - 1 - s) : s;
    // ---- input projection (independent of recurrence -> before poll) ----
    f32x4 acc0 = {0.f, 0.f, 0.f, 0.f}, acc1 = {0.f, 0.f, 0.f, 0.f};
#pragma unroll
    for (int kt = 0; kt < 2; ++kt) {
      bf16x8 xa = *(const bf16x8*)(xrow + t * 64 + kt * 32 + quad * 8);
      acc0 = MFMA(xa, wfi[0][kt], acc0);
      acc1 = MFMA(xa, wfi[1][kt], acc1);
    }
    if (s == 0) {
      for (int i = tid; i < 16 * 264 / 2; i += 256) ((uint32_t*)hbl)[i] = 0u;
    } else {
      const int tp = dir ? (t + 1) : (t - 1);     // previous step's t
      const uint64_t* src =
          (const uint64_t*)(h0 + ((size_t)tp * B_SZ + b0 + prow) * 512 + dir * H_SZ) + pcq;
      uint64_t v0, v1, v2, v3;
      for (;;) {
        v0 = ld64_agent(src);     v1 = ld64_agent(src + 1);
        v2 = ld64_agent(src + 2); v3 = ld64_agent(src + 3);
        if (okv(v0) && okv(v1) && okv(v2) && okv(v3)) break;
      }
      uint64_t* dst = (uint64_t*)&hbl[prow][pcq * 4];
      dst[0] = v0; dst[1] = v1; dst[2] = v2; dst[3] = v3;
    }
    __syncthreads();
    // ---- recurrent MFMAs (weights in registers, A from LDS) ----
#pragma unroll
    for (int kt = 0; kt < 8; ++kt) {
      bf16x8 ha = *(const bf16x8*)&hbl[l15][kt * 32 + quad * 8];
      acc0 = MFMA(ha, wfh[0][kt], acc0);
      acc0 = MFMA(ha, wfl[0][kt], acc0);
      acc1 = MFMA(ha, wfh[1][kt], acc1);
      acc1 = MFMA(ha, wfl[1][kt], acc1);
    }
    // ---- gates -> LDS (C/D layout: col=lane&15, row=quad*4+r) ----
#pragma unroll
    for (int r = 0; r < 4; ++r) {
      gl[quad * 4 + r][(wv * 2 + 0) * 16 + l15] = acc0[r];
      gl[quad * 4 + r][(wv * 2 + 1) * 16 + l15] = acc1[r];
    }
    __syncthreads();
    // ---- lane-owned gate combine; h store IS the exchange publish ----
    {
      float hv[2];
#pragma unroll
      for (int u = 0; u < 2; ++u) {
        float iv = sigm(gl[erow][0 * 32 + ecol + u] + bia[0][u]);
        float fv = sigm(gl[erow][1 * 32 + ecol + u] + bia[1][u]);
        float gv = tanhx(gl[erow][2 * 32 + ecol + u] + bia[2][u]);
        float ov = sigm(gl[erow][3 * 32 + ecol + u] + bia[3][u]);
        float cp = u ? c2.y : c2.x;
        float cn = fv * cp + iv * gv;
        if (u) c2.y = cn; else c2.x = cn;
        hv[u] = ov * tanhx(cn);
      }
      st32_agent((uint32_t*)(h0 + ((size_t)t * B_SZ + b0 + erow) * 512 + dir * H_SZ + gj),
                 pack_bf16x2(hv[0], hv[1]));
    }
    // no trailing sync needed: next iter writes hbl only (all hbl/gl readers
    // of this step have passed the two barriers above)
  }
}

// ---------------------------------------------------------------------------
// Layer 1 forward scan. 128 blocks = 16 bt x 8 ct, 512 threads (8 waves).
// Input h0[t] tiles prefetched with NORMAL cached loads (static data).
// Recurrent exchange via per-step ring hg1[bt][s][16][256], sentinel-filled,
// same flag-in-data protocol.
// ---------------------------------------------------------------------------
__global__ __launch_bounds__(512, 2) void l1_scan(
    const bf16_t* __restrict__ h0,
    const bf16_t* __restrict__ wih, const bf16_t* __restrict__ whhh,
    const bf16_t* __restrict__ whhl, const float* __restrict__ bias,
    bf16_t* __restrict__ h1f, bf16_t* __restrict__ hg1) {
  const int bt = blockIdx.x >> 3, ct = blockIdx.x & 7;
  bf16_t* hgs = hg1 + (size_t)bt * T_SZ * 4096;   // [s][16][256]

  const int tid = threadIdx.x;
  const int lane = tid & 63, wv = tid >> 6, l15 = lane & 15, quad = lane >> 4;
  const int b0 = bt * 16;

  __shared__ bf16_t ibl[2][16][520];
  __shared__ bf16_t hbl[16][264];
  __shared__ float  gl[16][132];

  const int gc = wv * 16 + l15;
  const int row = (gc >> 5) * H_SZ + ct * 32 + (gc & 31);
  bf16x8 wfi[16], wfh[8], wfl[8];
#pragma unroll
  for (int kt = 0; kt < 16; ++kt)
    wfi[kt] = *(const bf16x8*)(wih + (size_t)row * 512 + kt * 32 + quad * 8);
#pragma unroll
  for (int kt = 0; kt < 8; ++kt) {
    wfh[kt] = *(const bf16x8*)(whhh + (size_t)row * H_SZ + kt * 32 + quad * 8);
    wfl[kt] = *(const bf16x8*)(whhl + (size_t)row * H_SZ + kt * 32 + quad * 8);
  }
  const int et = tid & 255;
  const int erow = et >> 4, ecol = 2 * (et & 15);
  const int gj = ct * 32 + ecol;
  float bia[4][2];
#pragma unroll
  for (int g = 0; g < 4; ++g) {
    bia[g][0] = bias[g * H_SZ + gj];
    bia[g][1] = bias[g * H_SZ + gj + 1];
  }
  float2 c2 = {0.f, 0.f};
  // poll ownership: 512 threads -> row tid>>5, 2 u64 per thread
  const int prow = tid >> 5, pcq = (tid & 31) * 2;

  // stage ibl[0] <- h0[t=0]
  {
    const int r = tid >> 5, cc = (tid & 31) * 16;
    const bf16_t* src = h0 + ((size_t)(b0 + r)) * 512 + cc;
    *(bf16x8*)&ibl[0][r][cc]     = *(const bf16x8*)(src);
    *(bf16x8*)&ibl[0][r][cc + 8] = *(const bf16x8*)(src + 8);
  }
  __syncthreads();

  for (int s = 0; s < T_SZ; ++s) {
    const int cur = s & 1, nxt = cur ^ 1;
    if (s + 1 < T_SZ) {  // prefetch next input tile (cached, no dependence)
      const int r = tid >> 5, cc = (tid & 31) * 16;
      const bf16_t* src = h0 + ((size_t)(s + 1) * B_SZ + b0 + r) * 512 + cc;
      *(bf16x8*)&ibl[nxt][r][cc]     = *(const bf16x8*)(src);
      *(bf16x8*)&ibl[nxt][r][cc + 8] = *(const bf16x8*)(src + 8);
    }
    f32x4 acc = {0.f, 0.f, 0.f, 0.f};
#pragma unroll
    for (int kt = 0; kt < 16; ++kt) {
      bf16x8 a = *(const bf16x8*)&ibl[cur][l15][kt * 32 + quad * 8];
      acc = MFMA(a, wfi[kt], acc);
    }
    if (s == 0) {
      for (int i = tid; i < 16 * 264 / 2; i += 512) ((uint32_t*)hbl)[i] = 0u;
    } else {
      const uint64_t* src =
          (const uint64_t*)(hgs + (size_t)(s - 1) * 4096 + prow * H_SZ) + pcq;
      uint64_t v0, v1;
      for (;;) {
        v0 = ld64_agent(src); v1 = ld64_agent(src + 1);
        if (okv(v0) && okv(v1)) break;
      }
      uint64_t* dst = (uint64_t*)&hbl[prow][pcq * 4];
      dst[0] = v0; dst[1] = v1;
    }
    __syncthreads();
#pragma unroll
    for (int kt = 0; kt < 8; ++kt) {
      bf16x8 ha = *(const bf16x8*)&hbl[l15][kt * 32 + quad * 8];
      acc = MFMA(ha, wfh[kt], acc);
      acc = MFMA(ha, wfl[kt], acc);
    }
#pragma unroll
    for (int r = 0; r < 4; ++r) gl[quad * 4 + r][wv * 16 + l15] = acc[r];
    __syncthreads();
    if (tid < 256) {
      float hv[2];
#pragma unroll
      for (int u = 0; u < 2; ++u) {
        float iv = sigm(gl[erow][0 * 32 + ecol + u] + bia[0][u]);
        float fv = sigm(gl[erow][1 * 32 + ecol + u] + bia[1][u]);
        float gv = tanhx(gl[erow][2 * 32 + ecol + u] + bia[2][u]);
        float ov = sigm(gl[erow][3 * 32 + ecol + u] + bia[3][u]);
        float cp = u ? c2.y : c2.x;
        float cn = fv * cp + iv * gv;
        if (u) c2.y = cn; else c2.x = cn;
        hv[u] = ov * tanhx(cn);
      }
      uint32_t pk = pack_bf16x2(hv[0], hv[1]);
      st32_agent((uint32_t*)(hgs + (size_t)s * 4096 + erow * H_SZ + gj), pk);
      if (s == T_SZ - 1)
        *(uint32_t*)(h1f + (size_t)(b0 + erow) * H_SZ + gj) = pk;
    }
  }
}

// ---------------------------------------------------------------------------
// Layer 1 reverse direction: output needs only t=T-1 = ONE step from zero
// state -> pure input projection + gate combine.
// ---------------------------------------------------------------------------
__global__ __launch_bounds__(256) void l1b_step(
    const bf16_t* __restrict__ h0, const bf16_t* __restrict__ wih_r,
    const float* __restrict__ bias_r, bf16_t* __restrict__ h1b) {
  const int bt = blockIdx.x >> 2, ct = blockIdx.x & 3;
  const int tid = threadIdx.x, lane = tid & 63, wv = tid >> 6;
  const int l15 = lane & 15, quad = lane >> 4;
  const int c0 = ct * 64 + wv * 16;
  const bf16_t* arow = h0 + ((size_t)(T_SZ - 1) * B_SZ + bt * 16 + l15) * 512;
  f32x4 acc[4] = {{0,0,0,0},{0,0,0,0},{0,0,0,0},{0,0,0,0}};
#pragma unroll 4
  for (int kt = 0; kt < 16; ++kt) {
    bf16x8 a = *(const bf16x8*)(arow + kt * 32 + quad * 8);
#pragma unroll
    for (int g = 0; g < 4; ++g) {
      bf16x8 w = *(const bf16x8*)(wih_r + (size_t)(g * H_SZ + c0 + l15) * 512 + kt * 32 + quad * 8);
      acc[g] = MFMA(a, w, acc[g]);
    }
  }
  const int j = c0 + l15;
  const float bi = bias_r[j], bg = bias_r[2 * H_SZ + j], bo = bias_r[3 * H_SZ + j];
#pragma unroll
  for (int r = 0; r < 4; ++r) {
    const int row = bt * 16 + quad * 4 + r;
    float iv = sigm(acc[0][r] + bi);
    float gv = tanhx(acc[2][r] + bg);
    float ov = sigm(acc[3][r] + bo);
    float cn = iv * gv;  // f*0 + i*g
    h1b[(size_t)row * H_SZ + j] = (bf16_t)(ov * tanhx(cn));
  }
}

// ---------------------------------------------------------------------------
// prep + head
// ---------------------------------------------------------------------------
__global__ void k_cvt4(const float* __restrict__ s, bf16_t* __restrict__ d, int n4) {
  int i = blockIdx.x * 256 + threadIdx.x;
  if (i < n4) {
    float4 v = ((const float4*)s)[i];
    bf16x4 o; o[0] = (bf16_t)v.x; o[1] = (bf16_t)v.y; o[2] = (bf16_t)v.z; o[3] = (bf16_t)v.w;
    ((bf16x4*)d)[i] = o;
  }
}
__global__ void k_split(const float* __restrict__ s, bf16_t* __restrict__ hi,
                        bf16_t* __restrict__ lo, int n) {
  int i = blockIdx.x * 256 + threadIdx.x;
  if (i < n) {
    float v = s[i];
    bf16_t h = (bf16_t)v;
    hi[i] = h;
    lo[i] = (bf16_t)(v - (float)h);
  }
}
__global__ void k_bias(const float* __restrict__ a, const float* __restrict__ b,
                       float* __restrict__ d, int n) {
  int i = blockIdx.x * 256 + threadIdx.x;
  if (i < n) d[i] = a[i] + b[i];
}
__global__ void k_fill4(uint4* __restrict__ p, int n) {
  int i = blockIdx.x * 256 + threadIdx.x;
  if (i < n) p[i] = make_uint4(SENT32, SENT32, SENT32, SENT32);
}
__global__ void k_fc(const bf16_t* __restrict__ hf, const bf16_t* __restrict__ hb,
                     const float* __restrict__ fw, const float* __restrict__ fb,
                     float* __restrict__ out) {
  int b = threadIdx.x;
  float s = fb[0];
  const bf16_t* pf = hf + (size_t)b * H_SZ;
  const bf16_t* pb = hb + (size_t)b * H_SZ;
  for (int j = 0; j < H_SZ; ++j) s += fw[j] * (float)pf[j];
  for (int j = 0; j < H_SZ; ++j) s += fw[H_SZ + j] * (float)pb[j];
  out[b] = s;
}

extern "C" void kernel_launch(void* const* d_in, const int* in_sizes, int n_in,
                              void* d_out, int out_size, void* d_ws, size_t ws_size,
                              hipStream_t stream) {
  (void)in_sizes; (void)n_in; (void)out_size; (void)ws_size;
  const float* x      = (const float*)d_in[0];
  const float* wih[4] = {(const float*)d_in[1], (const float*)d_in[5],
                         (const float*)d_in[9], (const float*)d_in[13]};
  const float* whh[4] = {(const float*)d_in[2], (const float*)d_in[6],
                         (const float*)d_in[10], (const float*)d_in[14]};
  const float* bih[4] = {(const float*)d_in[3], (const float*)d_in[7],
                         (const float*)d_in[11], (const float*)d_in[15]};
  const float* bhh[4] = {(const float*)d_in[4], (const float*)d_in[8],
                         (const float*)d_in[12], (const float*)d_in[16]};
  const float* fcw = (const float*)d_in[17];
  const float* fcb = (const float*)d_in[18];
  float* out = (float*)d_out;

  char* p = (char*)d_ws;
  auto take = [&](size_t bytes) { char* r = p; p += (bytes + 255) & ~(size_t)255; return r; };
  const int KinL[4] = {64, 64, 512, 512};  // l0f, l0b, l1f, l1r
  bf16_t* wihb[4]; float* biasc[4]; bf16_t* whhhi[3]; bf16_t* whhlo[3];
  for (int k = 0; k < 4; ++k) {
    wihb[k]  = (bf16_t*)take((size_t)1024 * KinL[k] * 2);
    biasc[k] = (float*)take(1024 * 4);
  }
  for (int k = 0; k < 3; ++k) {
    whhhi[k] = (bf16_t*)take((size_t)1024 * 256 * 2);
    whhlo[k] = (bf16_t*)take((size_t)1024 * 256 * 2);
  }
  bf16_t* xbf = (bf16_t*)take((size_t)B_SZ * T_SZ * 64 * 2);
  bf16_t* h1f = (bf16_t*)take((size_t)B_SZ * H_SZ * 2);
  bf16_t* h1b = (bf16_t*)take((size_t)B_SZ * H_SZ * 2);
  // sentinel-filled region: h0 (128 MiB) + hg1 (64 MiB), contiguous
  char* sbeg = p;
  bf16_t* h0  = (bf16_t*)take((size_t)T_SZ * B_SZ * 512 * 2);       // 128 MiB
  bf16_t* hg1 = (bf16_t*)take((size_t)16 * T_SZ * 4096 * 2);        // 64 MiB
  size_t sbytes = (size_t)(p - sbeg);

  // ---- prep ----
  k_cvt4<<<dim3(8192), 256, 0, stream>>>(x, xbf, (B_SZ * T_SZ * 64) / 4);
  for (int k = 0; k < 4; ++k) {
    k_cvt4<<<dim3((1024 * KinL[k] / 4 + 255) / 256), 256, 0, stream>>>(
        wih[k], wihb[k], 1024 * KinL[k] / 4);
    k_bias<<<dim3(4), 256, 0, stream>>>(bih[k], bhh[k], biasc[k], 1024);
  }
  for (int k = 0; k < 3; ++k)
    k_split<<<dim3(1024), 256, 0, stream>>>(whh[k], whhhi[k], whhlo[k], 1024 * 256);
  {
    int n4 = (int)(sbytes / 16);   // NaN-sentinel fill (flag-in-data protocol)
    k_fill4<<<dim3((n4 + 255) / 256), 256, 0, stream>>>((uint4*)sbeg, n4);
  }

  // ---- scans ----
  l0_scan<<<dim3(256), 256, 0, stream>>>(
      xbf, wihb[0], whhhi[0], whhlo[0], biasc[0],
           wihb[1], whhhi[1], whhlo[1], biasc[1], h0);
  l1_scan<<<dim3(128), 512, 0, stream>>>(
      h0, wihb[2], whhhi[2], whhlo[2], biasc[2], h1f, hg1);
  l1b_step<<<dim3(64), 256, 0, stream>>>(h0, wihb[3], biasc[3], h1b);

  k_fc<<<dim3(1), 256, 0, stream>>>(h1f, h1b, fcw, fcb, out);
}

// Round 6
// 2081.983 us; speedup vs baseline: 21.3486x; 1.0930x over previous
//
#include <hip/hip_runtime.h>

typedef __bf16 bf16_t;
typedef bf16_t bf16x8 __attribute__((ext_vector_type(8)));
typedef bf16_t bf16x4 __attribute__((ext_vector_type(4)));
typedef float f32x4 __attribute__((ext_vector_type(4)));

#define B_SZ 256
#define T_SZ 512
#define H_SZ 256
#define SCOPE_AGENT __HIP_MEMORY_SCOPE_AGENT
#define SENT32 0x7FC17FC1u   // two bf16 NaNs; produced h is always finite

__device__ __forceinline__ float sigm(float x) { return 1.f / (1.f + __expf(-x)); }
__device__ __forceinline__ float tanhx(float x) {
  x = fminf(fmaxf(x, -15.f), 15.f);
  float e = __expf(-2.f * x);
  return (1.f - e) / (1.f + e);
}
__device__ __forceinline__ uint32_t pack_bf16x2(float a, float b) {
  union { bf16_t h[2]; uint32_t u; } v;
  v.h[0] = (bf16_t)a; v.h[1] = (bf16_t)b; return v.u;
}
__device__ __forceinline__ void st32_agent(uint32_t* p, uint32_t v) {
  __hip_atomic_store(p, v, __ATOMIC_RELAXED, SCOPE_AGENT);
}
__device__ __forceinline__ uint64_t ld64_agent(const uint64_t* p) {
  return __hip_atomic_load(p, __ATOMIC_RELAXED, SCOPE_AGENT);
}
__device__ __forceinline__ bool okv(uint64_t v) {
  return ((uint32_t)v != SENT32) & ((uint32_t)(v >> 32) != SENT32);
}
#define MFMA(a, b, c) __builtin_amdgcn_mfma_f32_16x16x32_bf16((a), (b), (c), 0, 0, 0)

// ---------------------------------------------------------------------------
// Layer 0 scan. 256 blocks, 512 threads (8 waves, 1 N-tile each).
// Block-id swizzle: ct = id>>5 so the 8 ct-siblings of a (dir,bt) group have
// ids ≡ same value mod 8 -> same XCD under round-robin dispatch (shared L2
// dedups the x tile and shortens exchange visibility). Weights register-
// resident (72 VGPR/lane). Flag-in-data exchange on h0[t] (NaN sentinel).
// ---------------------------------------------------------------------------
__global__ __launch_bounds__(512, 2) void l0_scan(
    const bf16_t* __restrict__ xbf,
    const bf16_t* __restrict__ wih_f, const bf16_t* __restrict__ whhhi_f,
    const bf16_t* __restrict__ whhlo_f, const float* __restrict__ bias_f,
    const bf16_t* __restrict__ wih_b, const bf16_t* __restrict__ whhhi_b,
    const bf16_t* __restrict__ whhlo_b, const float* __restrict__ bias_b,
    bf16_t* __restrict__ h0) {
  const int id = blockIdx.x;
  const int ct = id >> 5;            // XCD-locality swizzle
  const int g  = id & 31;
  const int dir = g >> 4, bt = g & 15;
  const bf16_t* __restrict__ wih  = dir ? wih_b : wih_f;
  const bf16_t* __restrict__ whhh = dir ? whhhi_b : whhhi_f;
  const bf16_t* __restrict__ whhl = dir ? whhlo_b : whhlo_f;
  const float*  __restrict__ bias = dir ? bias_b : bias_f;

  const int tid = threadIdx.x;
  const int lane = tid & 63, wv = tid >> 6, l15 = lane & 15, quad = lane >> 4;
  const int b0 = bt * 16;

  __shared__ bf16_t hbl[16][264];   // staged h_prev (528B stride, 16B-aligned)
  __shared__ float  gl[16][132];    // gate pre-acts

  // ---- register-resident weight fragments: wave wv owns N-tile wv ----
  const int gc = wv * 16 + l15;                    // gate-col 0..127
  const int row = (gc >> 5) * H_SZ + ct * 32 + (gc & 31);
  bf16x8 wfi[2], wfh[8], wfl[8];
#pragma unroll
  for (int kt = 0; kt < 2; ++kt)
    wfi[kt] = *(const bf16x8*)(wih + (size_t)row * 64 + kt * 32 + quad * 8);
#pragma unroll
  for (int kt = 0; kt < 8; ++kt) {
    wfh[kt] = *(const bf16x8*)(whhh + (size_t)row * H_SZ + kt * 32 + quad * 8);
    wfl[kt] = *(const bf16x8*)(whhl + (size_t)row * H_SZ + kt * 32 + quad * 8);
  }
  const int et = tid & 255;
  const int erow = et >> 4, ecol = 2 * (et & 15);
  const int gj = ct * 32 + ecol;
  float bia[4][2];
#pragma unroll
  for (int gg = 0; gg < 4; ++gg) {
    bia[gg][0] = bias[gg * H_SZ + gj];
    bia[gg][1] = bias[gg * H_SZ + gj + 1];
  }
  float2 c2 = {0.f, 0.f};
  const bf16_t* xrow = xbf + (size_t)(b0 + l15) * T_SZ * 64;
  // poll/stage ownership: 512 threads -> row tid>>5, 2 u64 each
  const int prow = tid >> 5, pcq = (tid & 31) * 2;

  for (int s = 0; s < T_SZ; ++s) {
    const int t = dir ? (T_SZ - 1 - s) : s;
    // ---- input projection (independent of recurrence -> before poll) ----
    f32x4 acc = {0.f, 0.f, 0.f, 0.f};
#pragma unroll
    for (int kt = 0; kt < 2; ++kt) {
      bf16x8 xa = *(const bf16x8*)(xrow + t * 64 + kt * 32 + quad * 8);
      acc = MFMA(xa, wfi[kt], acc);
    }
    if (s == 0) {
      for (int i = tid; i < 16 * 264 / 2; i += 512) ((uint32_t*)hbl)[i] = 0u;
    } else {
      const int tp = dir ? (t + 1) : (t - 1);     // previous step's t
      const uint64_t* src =
          (const uint64_t*)(h0 + ((size_t)tp * B_SZ + b0 + prow) * 512 + dir * H_SZ) + pcq;
      uint64_t v0, v1;
      for (;;) {
        v0 = ld64_agent(src); v1 = ld64_agent(src + 1);
        if (okv(v0) && okv(v1)) break;
      }
      uint64_t* dst = (uint64_t*)&hbl[prow][pcq * 4];
      dst[0] = v0; dst[1] = v1;
    }
    __syncthreads();
    // ---- recurrent MFMAs (weights in registers, A from LDS) ----
#pragma unroll
    for (int kt = 0; kt < 8; ++kt) {
      bf16x8 ha = *(const bf16x8*)&hbl[l15][kt * 32 + quad * 8];
      acc = MFMA(ha, wfh[kt], acc);
      acc = MFMA(ha, wfl[kt], acc);
    }
    // ---- gates -> LDS (C/D layout: col=lane&15, row=quad*4+r) ----
#pragma unroll
    for (int r = 0; r < 4; ++r) gl[quad * 4 + r][wv * 16 + l15] = acc[r];
    __syncthreads();
    // ---- lane-owned gate combine; h store IS the exchange publish ----
    if (tid < 256) {
      float hv[2];
#pragma unroll
      for (int u = 0; u < 2; ++u) {
        float iv = sigm(gl[erow][0 * 32 + ecol + u] + bia[0][u]);
        float fv = sigm(gl[erow][1 * 32 + ecol + u] + bia[1][u]);
        float gv = tanhx(gl[erow][2 * 32 + ecol + u] + bia[2][u]);
        float ov = sigm(gl[erow][3 * 32 + ecol + u] + bia[3][u]);
        float cp = u ? c2.y : c2.x;
        float cn = fv * cp + iv * gv;
        if (u) c2.y = cn; else c2.x = cn;
        hv[u] = ov * tanhx(cn);
      }
      st32_agent((uint32_t*)(h0 + ((size_t)t * B_SZ + b0 + erow) * 512 + dir * H_SZ + gj),
                 pack_bf16x2(hv[0], hv[1]));
    }
  }
}

// ---------------------------------------------------------------------------
// Layer 1 forward scan. 128 blocks (swizzled: ct = id>>4 -> siblings share
// an XCD, h0 prefetch dedups in L2), 512 threads (8 waves).
// Prefetch loads issue at loop top; their ds_write is AFTER the poll so the
// h0 L3 latency hides inside the exchange wait.
// ---------------------------------------------------------------------------
__global__ __launch_bounds__(512, 2) void l1_scan(
    const bf16_t* __restrict__ h0,
    const bf16_t* __restrict__ wih, const bf16_t* __restrict__ whhh,
    const bf16_t* __restrict__ whhl, const float* __restrict__ bias,
    bf16_t* __restrict__ h1f, bf16_t* __restrict__ hg1) {
  const int id = blockIdx.x;
  const int ct = id >> 4, bt = id & 15;       // XCD-locality swizzle
  bf16_t* hgs = hg1 + (size_t)bt * T_SZ * 4096;   // [s][16][256]

  const int tid = threadIdx.x;
  const int lane = tid & 63, wv = tid >> 6, l15 = lane & 15, quad = lane >> 4;
  const int b0 = bt * 16;

  __shared__ bf16_t ibl[2][16][520];
  __shared__ bf16_t hbl[16][264];
  __shared__ float  gl[16][132];

  const int gc = wv * 16 + l15;
  const int row = (gc >> 5) * H_SZ + ct * 32 + (gc & 31);
  bf16x8 wfi[16], wfh[8], wfl[8];
#pragma unroll
  for (int kt = 0; kt < 16; ++kt)
    wfi[kt] = *(const bf16x8*)(wih + (size_t)row * 512 + kt * 32 + quad * 8);
#pragma unroll
  for (int kt = 0; kt < 8; ++kt) {
    wfh[kt] = *(const bf16x8*)(whhh + (size_t)row * H_SZ + kt * 32 + quad * 8);
    wfl[kt] = *(const bf16x8*)(whhl + (size_t)row * H_SZ + kt * 32 + quad * 8);
  }
  const int et = tid & 255;
  const int erow = et >> 4, ecol = 2 * (et & 15);
  const int gj = ct * 32 + ecol;
  float bia[4][2];
#pragma unroll
  for (int g = 0; g < 4; ++g) {
    bia[g][0] = bias[g * H_SZ + gj];
    bia[g][1] = bias[g * H_SZ + gj + 1];
  }
  float2 c2 = {0.f, 0.f};
  const int prow = tid >> 5, pcq = (tid & 31) * 2;   // poll ownership
  const int fr = tid >> 5, fcc = (tid & 31) * 16;    // prefetch ownership

  // stage ibl[0] <- h0[t=0]
  {
    const bf16_t* src = h0 + ((size_t)(b0 + fr)) * 512 + fcc;
    *(bf16x8*)&ibl[0][fr][fcc]     = *(const bf16x8*)(src);
    *(bf16x8*)&ibl[0][fr][fcc + 8] = *(const bf16x8*)(src + 8);
  }
  __syncthreads();

  for (int s = 0; s < T_SZ; ++s) {
    const int cur = s & 1, nxt = cur ^ 1;
    // issue next-tile global loads NOW; ds_write deferred past the poll
    bf16x8 pf0, pf1;
    if (s + 1 < T_SZ) {
      const bf16_t* src = h0 + ((size_t)(s + 1) * B_SZ + b0 + fr) * 512 + fcc;
      pf0 = *(const bf16x8*)(src);
      pf1 = *(const bf16x8*)(src + 8);
    }
    // ---- input projection before poll ----
    f32x4 acc = {0.f, 0.f, 0.f, 0.f};
#pragma unroll
    for (int kt = 0; kt < 16; ++kt) {
      bf16x8 a = *(const bf16x8*)&ibl[cur][l15][kt * 32 + quad * 8];
      acc = MFMA(a, wfi[kt], acc);
    }
    if (s == 0) {
      for (int i = tid; i < 16 * 264 / 2; i += 512) ((uint32_t*)hbl)[i] = 0u;
    } else {
      const uint64_t* src =
          (const uint64_t*)(hgs + (size_t)(s - 1) * 4096 + prow * H_SZ) + pcq;
      uint64_t v0, v1;
      for (;;) {
        v0 = ld64_agent(src); v1 = ld64_agent(src + 1);
        if (okv(v0) && okv(v1)) break;
      }
      uint64_t* dst = (uint64_t*)&hbl[prow][pcq * 4];
      dst[0] = v0; dst[1] = v1;
    }
    // deferred prefetch ds_write (load latency absorbed by the poll)
    if (s + 1 < T_SZ) {
      *(bf16x8*)&ibl[nxt][fr][fcc]     = pf0;
      *(bf16x8*)&ibl[nxt][fr][fcc + 8] = pf1;
    }
    __syncthreads();
#pragma unroll
    for (int kt = 0; kt < 8; ++kt) {
      bf16x8 ha = *(const bf16x8*)&hbl[l15][kt * 32 + quad * 8];
      acc = MFMA(ha, wfh[kt], acc);
      acc = MFMA(ha, wfl[kt], acc);
    }
#pragma unroll
    for (int r = 0; r < 4; ++r) gl[quad * 4 + r][wv * 16 + l15] = acc[r];
    __syncthreads();
    if (tid < 256) {
      float hv[2];
#pragma unroll
      for (int u = 0; u < 2; ++u) {
        float iv = sigm(gl[erow][0 * 32 + ecol + u] + bia[0][u]);
        float fv = sigm(gl[erow][1 * 32 + ecol + u] + bia[1][u]);
        float gv = tanhx(gl[erow][2 * 32 + ecol + u] + bia[2][u]);
        float ov = sigm(gl[erow][3 * 32 + ecol + u] + bia[3][u]);
        float cp = u ? c2.y : c2.x;
        float cn = fv * cp + iv * gv;
        if (u) c2.y = cn; else c2.x = cn;
        hv[u] = ov * tanhx(cn);
      }
      uint32_t pk = pack_bf16x2(hv[0], hv[1]);
      st32_agent((uint32_t*)(hgs + (size_t)s * 4096 + erow * H_SZ + gj), pk);
      if (s == T_SZ - 1)
        *(uint32_t*)(h1f + (size_t)(b0 + erow) * H_SZ + gj) = pk;
    }
  }
}

// ---------------------------------------------------------------------------
// Layer 1 reverse direction: output needs only t=T-1 = ONE step from zero
// state -> pure input projection + gate combine.
// ---------------------------------------------------------------------------
__global__ __launch_bounds__(256) void l1b_step(
    const bf16_t* __restrict__ h0, const bf16_t* __restrict__ wih_r,
    const float* __restrict__ bias_r, bf16_t* __restrict__ h1b) {
  const int bt = blockIdx.x >> 2, ct = blockIdx.x & 3;
  const int tid = threadIdx.x, lane = tid & 63, wv = tid >> 6;
  const int l15 = lane & 15, quad = lane >> 4;
  const int c0 = ct * 64 + wv * 16;
  const bf16_t* arow = h0 + ((size_t)(T_SZ - 1) * B_SZ + bt * 16 + l15) * 512;
  f32x4 acc[4] = {{0,0,0,0},{0,0,0,0},{0,0,0,0},{0,0,0,0}};
#pragma unroll 4
  for (int kt = 0; kt < 16; ++kt) {
    bf16x8 a = *(const bf16x8*)(arow + kt * 32 + quad * 8);
#pragma unroll
    for (int g = 0; g < 4; ++g) {
      bf16x8 w = *(const bf16x8*)(wih_r + (size_t)(g * H_SZ + c0 + l15) * 512 + kt * 32 + quad * 8);
      acc[g] = MFMA(a, w, acc[g]);
    }
  }
  const int j = c0 + l15;
  const float bi = bias_r[j], bg = bias_r[2 * H_SZ + j], bo = bias_r[3 * H_SZ + j];
#pragma unroll
  for (int r = 0; r < 4; ++r) {
    const int row = bt * 16 + quad * 4 + r;
    float iv = sigm(acc[0][r] + bi);
    float gv = tanhx(acc[2][r] + bg);
    float ov = sigm(acc[3][r] + bo);
    float cn = iv * gv;  // f*0 + i*g
    h1b[(size_t)row * H_SZ + j] = (bf16_t)(ov * tanhx(cn));
  }
}

// ---------------------------------------------------------------------------
// prep + head
// ---------------------------------------------------------------------------
__global__ void k_cvt4(const float* __restrict__ s, bf16_t* __restrict__ d, int n4) {
  int i = blockIdx.x * 256 + threadIdx.x;
  if (i < n4) {
    float4 v = ((const float4*)s)[i];
    bf16x4 o; o[0] = (bf16_t)v.x; o[1] = (bf16_t)v.y; o[2] = (bf16_t)v.z; o[3] = (bf16_t)v.w;
    ((bf16x4*)d)[i] = o;
  }
}
__global__ void k_split(const float* __restrict__ s, bf16_t* __restrict__ hi,
                        bf16_t* __restrict__ lo, int n) {
  int i = blockIdx.x * 256 + threadIdx.x;
  if (i < n) {
    float v = s[i];
    bf16_t h = (bf16_t)v;
    hi[i] = h;
    lo[i] = (bf16_t)(v - (float)h);
  }
}
__global__ void k_bias(const float* __restrict__ a, const float* __restrict__ b,
                       float* __restrict__ d, int n) {
  int i = blockIdx.x * 256 + threadIdx.x;
  if (i < n) d[i] = a[i] + b[i];
}
__global__ void k_fill4(uint4* __restrict__ p, int n) {
  int i = blockIdx.x * 256 + threadIdx.x;
  if (i < n) p[i] = make_uint4(SENT32, SENT32, SENT32, SENT32);
}
__global__ void k_fc(const bf16_t* __restrict__ hf, const bf16_t* __restrict__ hb,
                     const float* __restrict__ fw, const float* __restrict__ fb,
                     float* __restrict__ out) {
  int b = threadIdx.x;
  float s = fb[0];
  const bf16_t* pf = hf + (size_t)b * H_SZ;
  const bf16_t* pb = hb + (size_t)b * H_SZ;
  for (int j = 0; j < H_SZ; ++j) s += fw[j] * (float)pf[j];
  for (int j = 0; j < H_SZ; ++j) s += fw[H_SZ + j] * (float)pb[j];
  out[b] = s;
}

extern "C" void kernel_launch(void* const* d_in, const int* in_sizes, int n_in,
                              void* d_out, int out_size, void* d_ws, size_t ws_size,
                              hipStream_t stream) {
  (void)in_sizes; (void)n_in; (void)out_size; (void)ws_size;
  const float* x      = (const float*)d_in[0];
  const float* wih[4] = {(const float*)d_in[1], (const float*)d_in[5],
                         (const float*)d_in[9], (const float*)d_in[13]};
  const float* whh[4] = {(const float*)d_in[2], (const float*)d_in[6],
                         (const float*)d_in[10], (const float*)d_in[14]};
  const float* bih[4] = {(const float*)d_in[3], (const float*)d_in[7],
                         (const float*)d_in[11], (const float*)d_in[15]};
  const float* bhh[4] = {(const float*)d_in[4], (const float*)d_in[8],
                         (const float*)d_in[12], (const float*)d_in[16]};
  const float* fcw = (const float*)d_in[17];
  const float* fcb = (const float*)d_in[18];
  float* out = (float*)d_out;

  char* p = (char*)d_ws;
  auto take = [&](size_t bytes) { char* r = p; p += (bytes + 255) & ~(size_t)255; return r; };
  const int KinL[4] = {64, 64, 512, 512};  // l0f, l0b, l1f, l1r
  bf16_t* wihb[4]; float* biasc[4]; bf16_t* whhhi[3]; bf16_t* whhlo[3];
  for (int k = 0; k < 4; ++k) {
    wihb[k]  = (bf16_t*)take((size_t)1024 * KinL[k] * 2);
    biasc[k] = (float*)take(1024 * 4);
  }
  for (int k = 0; k < 3; ++k) {
    whhhi[k] = (bf16_t*)take((size_t)1024 * 256 * 2);
    whhlo[k] = (bf16_t*)take((size_t)1024 * 256 * 2);
  }
  bf16_t* xbf = (bf16_t*)take((size_t)B_SZ * T_SZ * 64 * 2);
  bf16_t* h1f = (bf16_t*)take((size_t)B_SZ * H_SZ * 2);
  bf16_t* h1b = (bf16_t*)take((size_t)B_SZ * H_SZ * 2);
  // sentinel-filled region: h0 (128 MiB) + hg1 (64 MiB), contiguous
  char* sbeg = p;
  bf16_t* h0  = (bf16_t*)take((size_t)T_SZ * B_SZ * 512 * 2);       // 128 MiB
  bf16_t* hg1 = (bf16_t*)take((size_t)16 * T_SZ * 4096 * 2);        // 64 MiB
  size_t sbytes = (size_t)(p - sbeg);

  // ---- prep ----
  k_cvt4<<<dim3(8192), 256, 0, stream>>>(x, xbf, (B_SZ * T_SZ * 64) / 4);
  for (int k = 0; k < 4; ++k) {
    k_cvt4<<<dim3((1024 * KinL[k] / 4 + 255) / 256), 256, 0, stream>>>(
        wih[k], wihb[k], 1024 * KinL[k] / 4);
    k_bias<<<dim3(4), 256, 0, stream>>>(bih[k], bhh[k], biasc[k], 1024);
  }
  for (int k = 0; k < 3; ++k)
    k_split<<<dim3(1024), 256, 0, stream>>>(whh[k], whhhi[k], whhlo[k], 1024 * 256);
  {
    int n4 = (int)(sbytes / 16);   // NaN-sentinel fill (flag-in-data protocol)
    k_fill4<<<dim3((n4 + 255) / 256), 256, 0, stream>>>((uint4*)sbeg, n4);
  }

  // ---- scans ----
  l0_scan<<<dim3(256), 512, 0, stream>>>(
      xbf, wihb[0], whhhi[0], whhlo[0], biasc[0],
           wihb[1], whhhi[1], whhlo[1], biasc[1], h0);
  l1_scan<<<dim3(128), 512, 0, stream>>>(
      h0, wihb[2], whhhi[2], whhlo[2], biasc[2], h1f, hg1);
  l1b_step<<<dim3(64), 256, 0, stream>>>(h0, wihb[3], biasc[3], h1b);

  k_fc<<<dim3(1), 256, 0, stream>>>(h1f, h1b, fcw, fcb, out);
}